// Round 1
// baseline (810.527 us; speedup 1.0000x reference)
//
#include <hip/hip_runtime.h>
#include <hip/hip_cooperative_groups.h>
#include <hip/hip_bf16.h>
#include <cstdint>

namespace cg = cooperative_groups;

#define KDIM 1024
#define BDIM 8192
#define VDIM 2
#define NBLK 16  // KDIM / 64
#define MEGA_GRID 512

typedef __attribute__((ext_vector_type(8))) short short8;
typedef __attribute__((ext_vector_type(4))) float f32x4;

__device__ inline unsigned short f2bf(float x) {
  unsigned u = __builtin_bit_cast(unsigned, x);
  u = (u + 0x7FFFu + ((u >> 16) & 1u)) >> 16;
  return (unsigned short)u;
}

// Scratch layout inside the Mbf region (floats): per-level P^T buffers
#define SCR_L1 0        //  8 * 64*64   = 32768
#define SCR_L2 32768    //  4 * 128*128 = 65536
#define SCR_L3 98304    //  2 * 256*256 = 131072
#define SCR_L4 229376   //  1 * 512*512 = 262144
#define SCR_TOTAL 491520

// ---------------------------------------------------------------------------
// Combine phase bodies as device functions (shared by mega kernel + fallback).
// P: Pt[j][r] += sum_c MT[base+j][base+c] * A[base+h+r][base+c]
// Q: MT[base+j][base+h+r] += sum_c Pt[j][c] * MT[base+h+c][base+h+r]
// ---------------------------------------------------------------------------
__device__ void comb_p_tile(const float* __restrict__ A,
                            const float* __restrict__ MT,
                            float* __restrict__ Pt, int h, int bidx,
                            float (*Ls)[68], float (*Rs)[68]) {
  const int t = h >> 6;
  int b = bidx;
  const int kc = b % t; b /= t;
  const int rt = b % t; b /= t;
  const int jt = b % t; b /= t;
  const int c = b;
  const int base = c * 2 * h;

  const int tid = threadIdx.x;
  const int k4 = tid & 15;
  const int rw = tid >> 4;
#pragma unroll
  for (int p = 0; p < 4; ++p) {
    const int m = p * 16 + rw;
    float4 lv = *(const float4*)(MT + (size_t)(base + jt * 64 + m) * KDIM +
                                 base + kc * 64 + 4 * k4);
    Ls[4 * k4 + 0][m] = lv.x;
    Ls[4 * k4 + 1][m] = lv.y;
    Ls[4 * k4 + 2][m] = lv.z;
    Ls[4 * k4 + 3][m] = lv.w;
    float4 rv = *(const float4*)(A + (size_t)(base + h + rt * 64 + m) * KDIM +
                                 base + kc * 64 + 4 * k4);
    Rs[4 * k4 + 0][m] = rv.x;
    Rs[4 * k4 + 1][m] = rv.y;
    Rs[4 * k4 + 2][m] = rv.z;
    Rs[4 * k4 + 3][m] = rv.w;
  }
  __syncthreads();

  const int tm = tid >> 4;
  const int tn = tid & 15;
  float acc[4][4];
#pragma unroll
  for (int a = 0; a < 4; ++a)
#pragma unroll
    for (int bb = 0; bb < 4; ++bb) acc[a][bb] = 0.f;

#pragma unroll 4
  for (int k = 0; k < 64; ++k) {
    float4 av = *(const float4*)&Ls[k][4 * tm];
    float4 bv = *(const float4*)&Rs[k][4 * tn];
    const float aa[4] = {av.x, av.y, av.z, av.w};
    const float bb4[4] = {bv.x, bv.y, bv.z, bv.w};
#pragma unroll
    for (int a = 0; a < 4; ++a)
#pragma unroll
      for (int bb = 0; bb < 4; ++bb) acc[a][bb] += aa[a] * bb4[bb];
  }

  float* P0 = Pt + (size_t)c * h * h;
#pragma unroll
  for (int a = 0; a < 4; ++a)
#pragma unroll
    for (int bb = 0; bb < 4; ++bb)
      unsafeAtomicAdd(P0 + (size_t)(jt * 64 + 4 * tm + a) * h + rt * 64 + 4 * tn + bb,
                      acc[a][bb]);
}

__device__ void comb_q_tile(float* __restrict__ MT,
                            const float* __restrict__ Pt, int h, int bidx,
                            float (*Ls)[68], float (*Rs)[68]) {
  const int t = h >> 6;
  int b = bidx;
  const int kc = b % t; b /= t;
  const int rt = b % t; b /= t;
  const int jt = b % t; b /= t;
  const int c = b;
  const int base = c * 2 * h;

  const int tid = threadIdx.x;
  const int k4 = tid & 15;
  const int rw = tid >> 4;
  const float* P0 = Pt + (size_t)c * h * h;
#pragma unroll
  for (int p = 0; p < 4; ++p) {
    const int m = p * 16 + rw;
    float4 lv = *(const float4*)(P0 + (size_t)(jt * 64 + m) * h + kc * 64 + 4 * k4);
    Ls[4 * k4 + 0][m] = lv.x;
    Ls[4 * k4 + 1][m] = lv.y;
    Ls[4 * k4 + 2][m] = lv.z;
    Ls[4 * k4 + 3][m] = lv.w;
    const int kk = p * 16 + rw;
    *(float4*)&Rs[kk][4 * k4] =
        *(const float4*)(MT + (size_t)(base + h + kc * 64 + kk) * KDIM +
                         base + h + rt * 64 + 4 * k4);
  }
  __syncthreads();

  const int tm = tid >> 4;
  const int tn = tid & 15;
  float acc[4][4];
#pragma unroll
  for (int a = 0; a < 4; ++a)
#pragma unroll
    for (int bb = 0; bb < 4; ++bb) acc[a][bb] = 0.f;

#pragma unroll 4
  for (int k = 0; k < 64; ++k) {
    float4 av = *(const float4*)&Ls[k][4 * tm];
    float4 bv = *(const float4*)&Rs[k][4 * tn];
    const float aa[4] = {av.x, av.y, av.z, av.w};
    const float bb4[4] = {bv.x, bv.y, bv.z, bv.w};
#pragma unroll
    for (int a = 0; a < 4; ++a)
#pragma unroll
      for (int bb = 0; bb < 4; ++bb) acc[a][bb] += aa[a] * bb4[bb];
  }

#pragma unroll
  for (int a = 0; a < 4; ++a)
#pragma unroll
    for (int bb = 0; bb < 4; ++bb)
      unsafeAtomicAdd(MT + (size_t)(base + jt * 64 + 4 * tm + a) * KDIM +
                          base + h + rt * 64 + 4 * tn + bb,
                      acc[a][bb]);
}

// ---------------------------------------------------------------------------
// MEGA kernel: zero -> invert_diag -> 4 levels of (comb_p, comb_q) -> mt2bf,
// with grid-wide syncs. Replaces 11 serialized dispatches with 1.
// grid = 512 blocks x 256 thr, 34.8 KB LDS, __launch_bounds__(256,2):
// co-residency capacity >= 2 blocks/CU * 256 CU = 512.  All phase tile
// counts (8/32/128/512, 16 inverts, 256 transposes) fit in one pass.
// ---------------------------------------------------------------------------
__global__ __launch_bounds__(256, 2) void mega(const float* __restrict__ A,
                                               float* __restrict__ MT,
                                               float* __restrict__ scr,
                                               unsigned short* __restrict__ Mbf) {
  cg::grid_group grid = cg::this_grid();
  __shared__ float sh[2 * 64 * 68];  // 34816 B; aliased per phase
  float (*Ls)[68] = (float(*)[68])sh;
  float (*Rs)[68] = (float(*)[68])(sh + 64 * 68);

  // ---- phase 0: zero MT (atomic targets for comb_q) + scr (comb_p) ----
  {
    const float4 z4 = make_float4(0.f, 0.f, 0.f, 0.f);
    const int idx = blockIdx.x * 256 + threadIdx.x;
    const int stride = MEGA_GRID * 256;
    for (int i = idx; i < KDIM * KDIM / 4; i += stride)
      *(float4*)(MT + 4 * (size_t)i) = z4;
    for (int i = idx; i < SCR_TOTAL / 4; i += stride)
      *(float4*)(scr + 4 * (size_t)i) = z4;
  }
  grid.sync();

  // ---- phase 1: invert the 16 diagonal 64x64 unit-lower-tri blocks ----
  if (blockIdx.x < NBLK) {
    const int ib = blockIdx.x;
    const int base = ib * 64;
    float* As = sh;  // 4096 floats
    for (int i = threadIdx.x; i < 64 * 64; i += 256)
      As[i] = A[(size_t)(base + (i >> 6)) * KDIM + base + (i & 63)];
    __syncthreads();
    if (threadIdx.x < 64) {
      const int c = threadIdx.x;
      float m[64];
#pragma unroll
      for (int r = 0; r < 64; ++r) m[r] = (r == c) ? 1.f : 0.f;
#pragma unroll
      for (int r = 1; r < 64; ++r) {
        float acc0 = 0.f, acc1 = 0.f;
#pragma unroll
        for (int i = 0; i < 64; ++i) {
          if (i >= r) break;
          if (i & 1) acc1 += As[r * 64 + i] * m[i];
          else       acc0 += As[r * 64 + i] * m[i];
        }
        const float v = acc0 + acc1;
        m[r] = (r > c) ? v : m[r];
      }
#pragma unroll
      for (int r = 0; r < 64; r += 4) {
        float4 v = make_float4(m[r], m[r + 1], m[r + 2], m[r + 3]);
        *(float4*)(MT + (size_t)(base + c) * KDIM + base + r) = v;
      }
    }
  }
  grid.sync();

  // ---- phases 2..9: recursive doubling, levels h = 64,128,256,512 ----
  const int scroff[4] = {SCR_L1, SCR_L2, SCR_L3, SCR_L4};
#pragma unroll
  for (int lvl = 0; lvl < 4; ++lvl) {
    const int h = 64 << lvl;
    const int t = h >> 6;
    const int combines = NBLK >> (lvl + 1);
    const int ntiles = combines * t * t * t;  // 8, 32, 128, 512
    if (blockIdx.x < ntiles)
      comb_p_tile(A, MT, scr + scroff[lvl], h, blockIdx.x, Ls, Rs);
    grid.sync();
    if (blockIdx.x < ntiles)
      comb_q_tile(MT, scr + scroff[lvl], h, blockIdx.x, Ls, Rs);
    grid.sync();
  }

  // ---- phase 10: Mbf[i][k] = bf16(MT[k][i]) (transpose + convert) ----
  if (blockIdx.x < NBLK * NBLK) {
    const int ib = blockIdx.x & 15;
    const int jb = blockIdx.x >> 4;
    const int i0 = ib * 64, j0 = jb * 64;
    float (*tile)[65] = (float(*)[65])sh;  // 16.6 KB, fits in sh

    const int tr = threadIdx.x >> 4;
    const int tc = threadIdx.x & 15;
#pragma unroll
    for (int p = 0; p < 4; ++p) {
      const int rj = p * 16 + tr;
      float4 v = *(const float4*)(MT + (size_t)(j0 + rj) * KDIM + i0 + 4 * tc);
      tile[rj][4 * tc + 0] = v.x;
      tile[rj][4 * tc + 1] = v.y;
      tile[rj][4 * tc + 2] = v.z;
      tile[rj][4 * tc + 3] = v.w;
    }
    __syncthreads();
#pragma unroll
    for (int p = 0; p < 4; ++p) {
      const int il = p * 16 + tr;
      ushort4 o;
      o.x = f2bf(tile[4 * tc + 0][il]);
      o.y = f2bf(tile[4 * tc + 1][il]);
      o.z = f2bf(tile[4 * tc + 2][il]);
      o.w = f2bf(tile[4 * tc + 3][il]);
      *(ushort4*)(Mbf + (size_t)(i0 + il) * KDIM + j0 + 4 * tc) = o;
    }
  }
}

// ---------------------------------------------------------------------------
// Fallback path kernels (used only if cooperative launch is unavailable).
// ---------------------------------------------------------------------------
__global__ __launch_bounds__(256) void zero_ws(float* __restrict__ MT,
                                               float* __restrict__ scr) {
  const float4 z4 = make_float4(0.f, 0.f, 0.f, 0.f);
  const int stride = gridDim.x * blockDim.x;
  for (int i = blockIdx.x * blockDim.x + threadIdx.x; i < KDIM * KDIM / 4;
       i += stride)
    *(float4*)(MT + 4 * (size_t)i) = z4;
  for (int i = blockIdx.x * blockDim.x + threadIdx.x; i < SCR_TOTAL / 4;
       i += stride)
    *(float4*)(scr + 4 * (size_t)i) = z4;
}

__global__ __launch_bounds__(64) void invert_diag(const float* __restrict__ A,
                                                  float* __restrict__ MT) {
  const int ib = blockIdx.x;
  const int c = threadIdx.x;
  const int base = ib * 64;

  __shared__ float As[64 * 64];
  for (int r = 0; r < 64; ++r)
    As[r * 64 + c] = A[(size_t)(base + r) * KDIM + base + c];
  __syncthreads();

  float m[64];
#pragma unroll
  for (int r = 0; r < 64; ++r) m[r] = (r == c) ? 1.f : 0.f;
#pragma unroll
  for (int r = 1; r < 64; ++r) {
    float acc0 = 0.f, acc1 = 0.f;
#pragma unroll
    for (int i = 0; i < 64; ++i) {
      if (i >= r) break;
      if (i & 1) acc1 += As[r * 64 + i] * m[i];
      else       acc0 += As[r * 64 + i] * m[i];
    }
    const float v = acc0 + acc1;
    m[r] = (r > c) ? v : m[r];
  }
#pragma unroll
  for (int r = 0; r < 64; r += 4) {
    float4 v = make_float4(m[r], m[r + 1], m[r + 2], m[r + 3]);
    *(float4*)(MT + (size_t)(base + c) * KDIM + base + r) = v;
  }
}

__global__ __launch_bounds__(256) void comb_p(const float* __restrict__ A,
                                              const float* __restrict__ MT,
                                              float* __restrict__ Pt, int h) {
  __shared__ float Ls[64][68];
  __shared__ float Rs[64][68];
  comb_p_tile(A, MT, Pt, h, blockIdx.x, Ls, Rs);
}

__global__ __launch_bounds__(256) void comb_q(float* __restrict__ MT,
                                              const float* __restrict__ Pt,
                                              int h) {
  __shared__ float Ls[64][68];
  __shared__ float Rs[64][68];
  comb_q_tile(MT, Pt, h, blockIdx.x, Ls, Rs);
}

__global__ __launch_bounds__(256) void mt2bf(const float* __restrict__ MT,
                                             unsigned short* __restrict__ Mbf) {
  const int ib = blockIdx.x & 15;
  const int jb = blockIdx.x >> 4;
  const int i0 = ib * 64, j0 = jb * 64;
  __shared__ float tile[64][65];

  const int tr = threadIdx.x >> 4;
  const int tc = threadIdx.x & 15;
#pragma unroll
  for (int p = 0; p < 4; ++p) {
    const int rj = p * 16 + tr;
    float4 v = *(const float4*)(MT + (size_t)(j0 + rj) * KDIM + i0 + 4 * tc);
    tile[rj][4 * tc + 0] = v.x;
    tile[rj][4 * tc + 1] = v.y;
    tile[rj][4 * tc + 2] = v.z;
    tile[rj][4 * tc + 3] = v.w;
  }
  __syncthreads();
#pragma unroll
  for (int p = 0; p < 4; ++p) {
    const int il = p * 16 + tr;
    ushort4 o;
    o.x = f2bf(tile[4 * tc + 0][il]);
    o.y = f2bf(tile[4 * tc + 1][il]);
    o.z = f2bf(tile[4 * tc + 2][il]);
    o.w = f2bf(tile[4 * tc + 3][il]);
    *(ushort4*)(Mbf + (size_t)(i0 + il) * KDIM + j0 + 4 * tc) = o;
  }
}

// ---------------------------------------------------------------------------
// Kernel 2: bf16 MFMA GEMM.  C[b][i] = sum_k Z[b][k] * Mbf[i][k]   (NT)
// 128x128 tile, 4 waves (2x2 of 64x64), BK=64, mfma_f32_16x16x32_bf16.
// Load-balance: CU pairing is (wg, wg+256) which differ by xb+=32, same t7.
// Flipping ni for xb>=32 makes each CU's pair sum to a constant 18 k-blocks
// (was: same ni twice -> up to 32 vs avg 18 -> ~1.8x tail).
// ---------------------------------------------------------------------------
#define LDB 72

__global__ __launch_bounds__(256) void gemm_mfma(
    const float* __restrict__ Z, const unsigned short* __restrict__ Mbf,
    float* __restrict__ C) {
  __shared__ unsigned short As[128][LDB];
  __shared__ unsigned short Bs[128][LDB];

  const int wg = blockIdx.x;
  const int t7 = wg & 7;
  int ni = (t7 & 1) ? (7 - (t7 >> 1)) : (t7 >> 1);
  const int xb = wg >> 3;
  if (xb & 32) ni = 7 - ni;  // complementary work pairing across rounds
  const int b0 = xb * 128;
  const int i0 = ni * 128;

  const int tid = threadIdx.x;
  const int w = tid >> 6;
  const int lane = tid & 63;
  const int wr = w >> 1, wc = w & 1;
  const int mlane = lane & 15;
  const int q = lane >> 4;

  const int rq = tid >> 4, kq = tid & 15;
  const int cb = tid >> 3, ck = tid & 7;

  f32x4 acc[4][4];
#pragma unroll
  for (int a = 0; a < 4; ++a)
#pragma unroll
    for (int b = 0; b < 4; ++b) acc[a][b] = (f32x4){0.f, 0.f, 0.f, 0.f};

  const int nkb = 2 * (ni + 1);
  for (int kb = 0; kb < nkb; ++kb) {
    const int k0 = kb * 64;
#pragma unroll
    for (int p = 0; p < 8; ++p) {
      const int r = p * 16 + rq;
      float4 zv = *(const float4*)(Z + (size_t)(b0 + r) * KDIM + k0 + 4 * kq);
      ushort4 o;
      o.x = f2bf(zv.x);
      o.y = f2bf(zv.y);
      o.z = f2bf(zv.z);
      o.w = f2bf(zv.w);
      *(ushort4*)&As[r][4 * kq] = o;
    }
#pragma unroll
    for (int p = 0; p < 4; ++p) {
      const int c = p * 32 + cb;
      *(uint4*)&Bs[c][8 * ck] =
          *(const uint4*)(Mbf + (size_t)(i0 + c) * KDIM + k0 + 8 * ck);
    }
    __syncthreads();
#pragma unroll
    for (int ks = 0; ks < 2; ++ks) {
      const int kf = ks * 32 + q * 8;
      short8 av[4], bv[4];
#pragma unroll
      for (int a = 0; a < 4; ++a)
        av[a] = *(const short8*)&As[wr * 64 + 16 * a + mlane][kf];
#pragma unroll
      for (int b = 0; b < 4; ++b)
        bv[b] = *(const short8*)&Bs[wc * 64 + 16 * b + mlane][kf];
#pragma unroll
      for (int a = 0; a < 4; ++a)
#pragma unroll
        for (int b = 0; b < 4; ++b)
          acc[a][b] =
              __builtin_amdgcn_mfma_f32_16x16x32_bf16(av[a], bv[b], acc[a][b], 0, 0, 0);
    }
    __syncthreads();
  }

#pragma unroll
  for (int a = 0; a < 4; ++a) {
    const int row0 = b0 + wr * 64 + 16 * a + q * 4;
#pragma unroll
    for (int b = 0; b < 4; ++b) {
      const int col = i0 + wc * 64 + 16 * b + mlane;
      float* Cp = C + (size_t)row0 * KDIM + col;
      Cp[0 * KDIM] = acc[a][b][0];
      Cp[1 * KDIM] = acc[a][b][1];
      Cp[2 * KDIM] = acc[a][b][2];
      Cp[3 * KDIM] = acc[a][b][3];
    }
  }
}

// ---------------------------------------------------------------------------
// Kernel 3: per-sample rank-1 correction, in place on d_out.
// NOTE: __syncthreads is required — all threads must read gt=out[b][t]
// before the wave owning index t overwrites it.
// ---------------------------------------------------------------------------
__global__ __launch_bounds__(256) void correction_k(
    const float* __restrict__ z, const int* __restrict__ tgt,
    const int* __restrict__ var, const float* __restrict__ means,
    const float* __restrict__ lsc, const float* __restrict__ MT,
    float* __restrict__ out) {
  const int b = blockIdx.x;
  const int t = tgt[b];
  if (t < 0) return;
  const int v = var[b];
  const float mval = means[t * VDIM + v];
  const float sval = expf(lsc[t * VDIM + v]);
  const float zv = z[(size_t)b * KDIM + t];
  const float gt = out[(size_t)b * KDIM + t];
  const float coef = (mval + sval * zv) - gt;
  __syncthreads();
  const int i = threadIdx.x * 4;
  float4 g = *(float4*)(out + (size_t)b * KDIM + i);
  float4 mt = *(const float4*)(MT + (size_t)t * KDIM + i);
  g.x += coef * mt.x;
  g.y += coef * mt.y;
  g.z += coef * mt.z;
  g.w += coef * mt.w;
  *(float4*)(out + (size_t)b * KDIM + i) = g;
}

// ---------------------------------------------------------------------------
extern "C" void kernel_launch(void* const* d_in, const int* in_sizes, int n_in,
                              void* d_out, int out_size, void* d_ws,
                              size_t ws_size, hipStream_t stream) {
  const float* z = (const float*)d_in[0];
  const int* tgt = (const int*)d_in[1];
  const int* var = (const int*)d_in[2];
  const float* A = (const float*)d_in[3];
  const float* means = (const float*)d_in[4];
  const float* lsc = (const float*)d_in[5];
  float* out = (float*)d_out;

  float* MT = (float*)d_ws;  // 4 MB fp32 (M^T = column-major M)
  float* scr = (float*)((char*)d_ws + (size_t)KDIM * KDIM * 4);  // 2 MB region
  unsigned short* Mbf = (unsigned short*)scr;  // reused after combines finish

  void* margs[] = {(void*)&A, (void*)&MT, (void*)&scr, (void*)&Mbf};
  hipError_t cerr = hipLaunchCooperativeKernel(
      (const void*)mega, dim3(MEGA_GRID), dim3(256), margs, 0u, stream);

  if (cerr != hipSuccess) {
    // Fallback: original 11-dispatch path.
    hipLaunchKernelGGL(zero_ws, dim3(128), dim3(256), 0, stream, MT, scr);
    hipLaunchKernelGGL(invert_diag, dim3(NBLK), dim3(64), 0, stream, A, MT);
    const int scroff[4] = {SCR_L1, SCR_L2, SCR_L3, SCR_L4};
    for (int lv = 0; lv < 4; ++lv) {
      const int h = 64 << lv;
      const int t = h >> 6;
      const int combines = NBLK >> (lv + 1);
      const int grid = combines * t * t * t;
      hipLaunchKernelGGL(comb_p, dim3(grid), dim3(256), 0, stream, A, MT,
                         scr + scroff[lv], h);
      hipLaunchKernelGGL(comb_q, dim3(grid), dim3(256), 0, stream, MT,
                         scr + scroff[lv], h);
    }
    hipLaunchKernelGGL(mt2bf, dim3(NBLK * NBLK), dim3(256), 0, stream, MT, Mbf);
  }

  hipLaunchKernelGGL(gemm_mfma, dim3((BDIM / 128) * (KDIM / 128)), dim3(256), 0,
                     stream, z, Mbf, out);
  hipLaunchKernelGGL(correction_k, dim3(BDIM), dim3(256), 0, stream, z, tgt,
                     var, means, lsc, MT, out);
}

// Round 2
// 281.142 us; speedup vs baseline: 2.8830x; 2.8830x over previous
//
#include <hip/hip_runtime.h>
#include <hip/hip_bf16.h>
#include <cstdint>

#define KDIM 1024
#define BDIM 8192
#define VDIM 2
#define NBLK 16  // KDIM / 64

typedef __attribute__((ext_vector_type(8))) short short8;
typedef __attribute__((ext_vector_type(4))) float f32x4;

__device__ inline unsigned short f2bf(float x) {
  unsigned u = __builtin_bit_cast(unsigned, x);
  u = (u + 0x7FFFu + ((u >> 16) & 1u)) >> 16;
  return (unsigned short)u;
}

// Scratch layout (floats) in the 2MB scr region: P^T buffers for lv2/lv3 only
// (lv0/lv1 are fused single-kernel and keep P in LDS).
#define SCR_L3 98304    //  2 * 256*256 = 131072 floats
#define SCR_L4 229376   //  1 * 512*512 = 262144 floats
#define SCR_TOTAL 491520

// 64x64 fp32 tile MAC: acc[a][b] += sum_k Ls[k][4tm+a] * Rs[k][4tn+b]
__device__ __forceinline__ void mac64(const float (*Ls)[68], const float (*Rs)[68],
                                      int tm, int tn, float acc[4][4]) {
#pragma unroll 4
  for (int k = 0; k < 64; ++k) {
    const float4 av = *(const float4*)&Ls[k][4 * tm];
    const float4 bv = *(const float4*)&Rs[k][4 * tn];
    const float aa[4] = {av.x, av.y, av.z, av.w};
    const float bb4[4] = {bv.x, bv.y, bv.z, bv.w};
#pragma unroll
    for (int a = 0; a < 4; ++a)
#pragma unroll
      for (int b = 0; b < 4; ++b) acc[a][b] += aa[a] * bb4[b];
  }
}

// ---------------------------------------------------------------------------
// prep: blocks 0..15 invert the diagonal 64x64 unit-lower-tri blocks of
// (I - A) into MT (column c of T = contiguous MT row). Blocks 16+ zero the
// off-diagonal 64-blocks of MT (atomic targets for lv2/lv3 Q + the upper-tri
// zeros consumed via mt2bf/gemm), zero the lv2/lv3 P scratch, and convert
// Z to bf16 (if workspace allows). All independent -> one dispatch.
// ---------------------------------------------------------------------------
__global__ __launch_bounds__(256) void prep(const float* __restrict__ A,
                                            float* __restrict__ MT,
                                            float* __restrict__ scr,
                                            const float* __restrict__ Z,
                                            unsigned short* __restrict__ Zbf,
                                            int do_zbf) {
  __shared__ float As[64 * 64];
  const int bid = blockIdx.x;

  if (bid < NBLK) {
    const int base = bid * 64;
    for (int i = threadIdx.x; i < 64 * 64; i += 256)
      As[i] = A[(size_t)(base + (i >> 6)) * KDIM + base + (i & 63)];
    __syncthreads();
    if (threadIdx.x < 64) {
      const int c = threadIdx.x;
      float m[64];
#pragma unroll
      for (int r = 0; r < 64; ++r) m[r] = (r == c) ? 1.f : 0.f;
#pragma unroll
      for (int r = 1; r < 64; ++r) {
        float acc0 = 0.f, acc1 = 0.f;
#pragma unroll
        for (int i = 0; i < 64; ++i) {
          if (i >= r) break;
          if (i & 1) acc1 += As[r * 64 + i] * m[i];
          else       acc0 += As[r * 64 + i] * m[i];
        }
        const float v = acc0 + acc1;
        m[r] = (r > c) ? v : m[r];
      }
#pragma unroll
      for (int r = 0; r < 64; r += 4) {
        float4 v = make_float4(m[r], m[r + 1], m[r + 2], m[r + 3]);
        *(float4*)(MT + (size_t)(base + c) * KDIM + base + r) = v;
      }
    }
    return;
  }

  const int wid = bid - NBLK;
  const int nw = gridDim.x - NBLK;
  const int idx0 = wid * 256 + threadIdx.x;
  const int stride = nw * 256;
  const float4 z4 = make_float4(0.f, 0.f, 0.f, 0.f);

  // MT off-diagonal zero: 240 blocks x 1024 float4
  for (int i = idx0; i < 240 * 1024; i += stride) {
    const int blk = i >> 10, off = i & 1023;
    const int bi = blk / 15;
    int bj = blk % 15;
    bj += (bj >= bi);
    *(float4*)(MT + (size_t)(bi * 64 + (off >> 4)) * KDIM + bj * 64 + 4 * (off & 15)) = z4;
  }
  // scratch zero for lv2/lv3 split-K atomics
  for (int i = idx0; i < (SCR_TOTAL - SCR_L3) / 4; i += stride)
    *(float4*)(scr + SCR_L3 + 4 * (size_t)i) = z4;
  // Z -> bf16
  if (do_zbf) {
    for (int i = idx0; i < BDIM * KDIM / 4; i += stride) {
      float4 v = *(const float4*)(Z + 4 * (size_t)i);
      ushort4 o;
      o.x = f2bf(v.x);
      o.y = f2bf(v.y);
      o.z = f2bf(v.z);
      o.w = f2bf(v.w);
      *(ushort4*)(Zbf + 4 * (size_t)i) = o;
    }
  }
}

// ---------------------------------------------------------------------------
// Level 0 fused (h=64, t=1): one block per combine c (grid 8).
// P = (A21*M11)^T kept in LDS, then Q = (M22*P)^T written directly (no atomics).
// ---------------------------------------------------------------------------
__global__ __launch_bounds__(256) void comb_lv0(const float* __restrict__ A,
                                                float* __restrict__ MT) {
  const int c = blockIdx.x;
  const int base = c * 128;
  __shared__ float Ls[64][68];
  __shared__ float Rs[64][68];
  __shared__ float Ps[64][68];

  const int tid = threadIdx.x;
  const int k4 = tid & 15;
  const int rw = tid >> 4;
#pragma unroll
  for (int p = 0; p < 4; ++p) {
    const int m = p * 16 + rw;
    float4 lv = *(const float4*)(MT + (size_t)(base + m) * KDIM + base + 4 * k4);
    Ls[4 * k4 + 0][m] = lv.x;
    Ls[4 * k4 + 1][m] = lv.y;
    Ls[4 * k4 + 2][m] = lv.z;
    Ls[4 * k4 + 3][m] = lv.w;
    float4 rv = *(const float4*)(A + (size_t)(base + 64 + m) * KDIM + base + 4 * k4);
    Rs[4 * k4 + 0][m] = rv.x;
    Rs[4 * k4 + 1][m] = rv.y;
    Rs[4 * k4 + 2][m] = rv.z;
    Rs[4 * k4 + 3][m] = rv.w;
  }
  __syncthreads();

  const int tm = tid >> 4;
  const int tn = tid & 15;
  float acc[4][4];
#pragma unroll
  for (int a = 0; a < 4; ++a)
#pragma unroll
    for (int b = 0; b < 4; ++b) acc[a][b] = 0.f;
  mac64(Ls, Rs, tm, tn, acc);
  __syncthreads();  // all MACs done before Rs is restaged

  // Ps[r][j] = P[j][r]  (Ls-format for the Q MAC)
#pragma unroll
  for (int a = 0; a < 4; ++a)
#pragma unroll
    for (int b = 0; b < 4; ++b) Ps[4 * tn + b][4 * tm + a] = acc[a][b];
  // Rs <- MT22 (k-rows, r-cols)
#pragma unroll
  for (int p = 0; p < 4; ++p) {
    const int kk = p * 16 + rw;
    *(float4*)&Rs[kk][4 * k4] =
        *(const float4*)(MT + (size_t)(base + 64 + kk) * KDIM + base + 64 + 4 * k4);
  }
  __syncthreads();

#pragma unroll
  for (int a = 0; a < 4; ++a)
#pragma unroll
    for (int b = 0; b < 4; ++b) acc[a][b] = 0.f;
  mac64(Ps, Rs, tm, tn, acc);

#pragma unroll
  for (int a = 0; a < 4; ++a)
#pragma unroll
    for (int b = 0; b < 4; ++b)
      MT[(size_t)(base + 4 * tm + a) * KDIM + base + 64 + 4 * tn + b] = acc[a][b];
}

// ---------------------------------------------------------------------------
// Level 1 fused (h=128, t=2): one block per (combine c, jt) (grid 8).
// P row-panel (64 x 128) kept in LDS, then both Q tiles written directly.
// ---------------------------------------------------------------------------
__global__ __launch_bounds__(256) void comb_lv1(const float* __restrict__ A,
                                                float* __restrict__ MT) {
  const int c = blockIdx.x >> 1;
  const int jt = blockIdx.x & 1;
  const int base = c * 256;
  __shared__ float Ls[64][68];
  __shared__ float Rs[64][68];
  __shared__ float Ps[128][68];

  const int tid = threadIdx.x;
  const int k4 = tid & 15;
  const int rw = tid >> 4;
  const int tm = tid >> 4;
  const int tn = tid & 15;

  // ---- P panel: for rt, accumulate over kc ----
  for (int rt = 0; rt < 2; ++rt) {
    float acc[4][4];
#pragma unroll
    for (int a = 0; a < 4; ++a)
#pragma unroll
      for (int b = 0; b < 4; ++b) acc[a][b] = 0.f;
    for (int kc = 0; kc < 2; ++kc) {
#pragma unroll
      for (int p = 0; p < 4; ++p) {
        const int m = p * 16 + rw;
        float4 lv = *(const float4*)(MT + (size_t)(base + jt * 64 + m) * KDIM +
                                     base + kc * 64 + 4 * k4);
        Ls[4 * k4 + 0][m] = lv.x;
        Ls[4 * k4 + 1][m] = lv.y;
        Ls[4 * k4 + 2][m] = lv.z;
        Ls[4 * k4 + 3][m] = lv.w;
        float4 rv = *(const float4*)(A + (size_t)(base + 128 + rt * 64 + m) * KDIM +
                                     base + kc * 64 + 4 * k4);
        Rs[4 * k4 + 0][m] = rv.x;
        Rs[4 * k4 + 1][m] = rv.y;
        Rs[4 * k4 + 2][m] = rv.z;
        Rs[4 * k4 + 3][m] = rv.w;
      }
      __syncthreads();
      mac64(Ls, Rs, tm, tn, acc);
      __syncthreads();
    }
#pragma unroll
    for (int a = 0; a < 4; ++a)
#pragma unroll
      for (int b = 0; b < 4; ++b) Ps[rt * 64 + 4 * tn + b][4 * tm + a] = acc[a][b];
  }
  __syncthreads();

  // ---- Q tiles: for rt2, accumulate over kc (P from LDS) ----
  for (int rt2 = 0; rt2 < 2; ++rt2) {
    float acc[4][4];
#pragma unroll
    for (int a = 0; a < 4; ++a)
#pragma unroll
      for (int b = 0; b < 4; ++b) acc[a][b] = 0.f;
    for (int kc = 0; kc < 2; ++kc) {
#pragma unroll
      for (int p = 0; p < 4; ++p) {
        const int kk = p * 16 + rw;
        *(float4*)&Rs[kk][4 * k4] =
            *(const float4*)(MT + (size_t)(base + 128 + kc * 64 + kk) * KDIM +
                             base + 128 + rt2 * 64 + 4 * k4);
      }
      __syncthreads();
      mac64((const float(*)[68])&Ps[kc * 64], Rs, tm, tn, acc);
      __syncthreads();
    }
#pragma unroll
    for (int a = 0; a < 4; ++a)
#pragma unroll
      for (int b = 0; b < 4; ++b)
        MT[(size_t)(base + jt * 64 + 4 * tm + a) * KDIM + base + 128 + rt2 * 64 +
           4 * tn + b] = acc[a][b];
  }
}

// ---------------------------------------------------------------------------
// Levels 2/3: split-K atomic two-phase (grids 128 / 512).
// P: Pt[j][r] += sum_c MT[base+j][base+c] * A[base+h+r][base+c]
// ---------------------------------------------------------------------------
__global__ __launch_bounds__(256) void comb_p(const float* __restrict__ A,
                                              const float* __restrict__ MT,
                                              float* __restrict__ Pt, int h) {
  const int t = h >> 6;
  int b = blockIdx.x;
  const int kc = b % t; b /= t;
  const int rt = b % t; b /= t;
  const int jt = b % t; b /= t;
  const int c = b;
  const int base = c * 2 * h;

  __shared__ float Ls[64][68];
  __shared__ float Rs[64][68];

  const int tid = threadIdx.x;
  const int k4 = tid & 15;
  const int rw = tid >> 4;
#pragma unroll
  for (int p = 0; p < 4; ++p) {
    const int m = p * 16 + rw;
    float4 lv = *(const float4*)(MT + (size_t)(base + jt * 64 + m) * KDIM +
                                 base + kc * 64 + 4 * k4);
    Ls[4 * k4 + 0][m] = lv.x;
    Ls[4 * k4 + 1][m] = lv.y;
    Ls[4 * k4 + 2][m] = lv.z;
    Ls[4 * k4 + 3][m] = lv.w;
    float4 rv = *(const float4*)(A + (size_t)(base + h + rt * 64 + m) * KDIM +
                                 base + kc * 64 + 4 * k4);
    Rs[4 * k4 + 0][m] = rv.x;
    Rs[4 * k4 + 1][m] = rv.y;
    Rs[4 * k4 + 2][m] = rv.z;
    Rs[4 * k4 + 3][m] = rv.w;
  }
  __syncthreads();

  const int tm = tid >> 4;
  const int tn = tid & 15;
  float acc[4][4];
#pragma unroll
  for (int a = 0; a < 4; ++a)
#pragma unroll
    for (int b2 = 0; b2 < 4; ++b2) acc[a][b2] = 0.f;
  mac64(Ls, Rs, tm, tn, acc);

  float* P0 = Pt + (size_t)c * h * h;
#pragma unroll
  for (int a = 0; a < 4; ++a)
#pragma unroll
    for (int b2 = 0; b2 < 4; ++b2)
      unsafeAtomicAdd(P0 + (size_t)(jt * 64 + 4 * tm + a) * h + rt * 64 + 4 * tn + b2,
                      acc[a][b2]);
}

__global__ __launch_bounds__(256) void comb_q(float* __restrict__ MT,
                                              const float* __restrict__ Pt,
                                              int h) {
  const int t = h >> 6;
  int b = blockIdx.x;
  const int kc = b % t; b /= t;
  const int rt = b % t; b /= t;
  const int jt = b % t; b /= t;
  const int c = b;
  const int base = c * 2 * h;

  __shared__ float Ls[64][68];
  __shared__ float Rs[64][68];

  const int tid = threadIdx.x;
  const int k4 = tid & 15;
  const int rw = tid >> 4;
  const float* P0 = Pt + (size_t)c * h * h;
#pragma unroll
  for (int p = 0; p < 4; ++p) {
    const int m = p * 16 + rw;
    float4 lv = *(const float4*)(P0 + (size_t)(jt * 64 + m) * h + kc * 64 + 4 * k4);
    Ls[4 * k4 + 0][m] = lv.x;
    Ls[4 * k4 + 1][m] = lv.y;
    Ls[4 * k4 + 2][m] = lv.z;
    Ls[4 * k4 + 3][m] = lv.w;
    const int kk = p * 16 + rw;
    *(float4*)&Rs[kk][4 * k4] =
        *(const float4*)(MT + (size_t)(base + h + kc * 64 + kk) * KDIM +
                         base + h + rt * 64 + 4 * k4);
  }
  __syncthreads();

  const int tm = tid >> 4;
  const int tn = tid & 15;
  float acc[4][4];
#pragma unroll
  for (int a = 0; a < 4; ++a)
#pragma unroll
    for (int b2 = 0; b2 < 4; ++b2) acc[a][b2] = 0.f;
  mac64(Ls, Rs, tm, tn, acc);

#pragma unroll
  for (int a = 0; a < 4; ++a)
#pragma unroll
    for (int b2 = 0; b2 < 4; ++b2)
      unsafeAtomicAdd(MT + (size_t)(base + jt * 64 + 4 * tm + a) * KDIM +
                          base + h + rt * 64 + 4 * tn + b2,
                      acc[a][b2]);
}

// ---------------------------------------------------------------------------
// Mbf[i][k] = bf16(MT[k][i])  — transpose+convert, 64x64 tiles.
// ---------------------------------------------------------------------------
__global__ __launch_bounds__(256) void mt2bf(const float* __restrict__ MT,
                                             unsigned short* __restrict__ Mbf) {
  const int ib = blockIdx.x & 15;
  const int jb = blockIdx.x >> 4;
  const int i0 = ib * 64, j0 = jb * 64;
  __shared__ float tile[64][65];

  const int tr = threadIdx.x >> 4;
  const int tc = threadIdx.x & 15;
#pragma unroll
  for (int p = 0; p < 4; ++p) {
    const int rj = p * 16 + tr;
    float4 v = *(const float4*)(MT + (size_t)(j0 + rj) * KDIM + i0 + 4 * tc);
    tile[rj][4 * tc + 0] = v.x;
    tile[rj][4 * tc + 1] = v.y;
    tile[rj][4 * tc + 2] = v.z;
    tile[rj][4 * tc + 3] = v.w;
  }
  __syncthreads();
#pragma unroll
  for (int p = 0; p < 4; ++p) {
    const int il = p * 16 + tr;
    ushort4 o;
    o.x = f2bf(tile[4 * tc + 0][il]);
    o.y = f2bf(tile[4 * tc + 1][il]);
    o.z = f2bf(tile[4 * tc + 2][il]);
    o.w = f2bf(tile[4 * tc + 3][il]);
    *(ushort4*)(Mbf + (size_t)(i0 + il) * KDIM + j0 + 4 * tc) = o;
  }
}

// ---------------------------------------------------------------------------
// bf16 MFMA GEMM.  C[b][i] = sum_k Z[b][k] * Mbf[i][k]   (NT)
// 128x128 tile, 4 waves (2x2 of 64x64), BK=64, mfma_f32_16x16x32_bf16.
// Index decode: d%8 = xb%8 -> all 8 ni-blocks of an xb group land on one XCD
// (L2 locality for the Z panel). xb bit-5 flips ni -> the CU pair (d, d+256)
// sums to a constant 18 K-units (was: identical ni -> ~1.8x imbalance tail).
// ZBF=1 reads pre-converted bf16 Z (half the A fetch, no f2bf in the loop).
// ---------------------------------------------------------------------------
#define LDB 72

template <int ZBF>
__global__ __launch_bounds__(256) void gemm_mfma(
    const float* __restrict__ Z, const unsigned short* __restrict__ Zbf,
    const unsigned short* __restrict__ Mbf, float* __restrict__ C) {
  __shared__ unsigned short As[128][LDB];
  __shared__ unsigned short Bs[128][LDB];

  const int d = blockIdx.x;
  const int xbl = d & 7;
  const int nir = (d >> 3) & 7;
  const int xbh = d >> 6;
  const int xb = xbh * 8 + xbl;
  const int ni = (xb & 32) ? (7 - nir) : nir;
  const int b0 = xb * 128;
  const int i0 = ni * 128;

  const int tid = threadIdx.x;
  const int w = tid >> 6;
  const int lane = tid & 63;
  const int wr = w >> 1, wc = w & 1;
  const int mlane = lane & 15;
  const int q = lane >> 4;

  const int rq = tid >> 4, kq = tid & 15;
  const int cb = tid >> 3, ck = tid & 7;

  f32x4 acc[4][4];
#pragma unroll
  for (int a = 0; a < 4; ++a)
#pragma unroll
    for (int b = 0; b < 4; ++b) acc[a][b] = (f32x4){0.f, 0.f, 0.f, 0.f};

  const int nkb = 2 * (ni + 1);
  for (int kb = 0; kb < nkb; ++kb) {
    const int k0 = kb * 64;
    if (ZBF) {
#pragma unroll
      for (int p = 0; p < 4; ++p) {
        const int r = p * 32 + cb;
        *(uint4*)&As[r][8 * ck] =
            *(const uint4*)(Zbf + (size_t)(b0 + r) * KDIM + k0 + 8 * ck);
      }
    } else {
#pragma unroll
      for (int p = 0; p < 8; ++p) {
        const int r = p * 16 + rq;
        float4 zv = *(const float4*)(Z + (size_t)(b0 + r) * KDIM + k0 + 4 * kq);
        ushort4 o;
        o.x = f2bf(zv.x);
        o.y = f2bf(zv.y);
        o.z = f2bf(zv.z);
        o.w = f2bf(zv.w);
        *(ushort4*)&As[r][4 * kq] = o;
      }
    }
#pragma unroll
    for (int p = 0; p < 4; ++p) {
      const int c = p * 32 + cb;
      *(uint4*)&Bs[c][8 * ck] =
          *(const uint4*)(Mbf + (size_t)(i0 + c) * KDIM + k0 + 8 * ck);
    }
    __syncthreads();
#pragma unroll
    for (int ks = 0; ks < 2; ++ks) {
      const int kf = ks * 32 + q * 8;
      short8 av[4], bv[4];
#pragma unroll
      for (int a = 0; a < 4; ++a)
        av[a] = *(const short8*)&As[wr * 64 + 16 * a + mlane][kf];
#pragma unroll
      for (int b = 0; b < 4; ++b)
        bv[b] = *(const short8*)&Bs[wc * 64 + 16 * b + mlane][kf];
#pragma unroll
      for (int a = 0; a < 4; ++a)
#pragma unroll
        for (int b = 0; b < 4; ++b)
          acc[a][b] =
              __builtin_amdgcn_mfma_f32_16x16x32_bf16(av[a], bv[b], acc[a][b], 0, 0, 0);
    }
    __syncthreads();
  }

#pragma unroll
  for (int a = 0; a < 4; ++a) {
    const int row0 = b0 + wr * 64 + 16 * a + q * 4;
#pragma unroll
    for (int b = 0; b < 4; ++b) {
      const int col = i0 + wc * 64 + 16 * b + mlane;
      float* Cp = C + (size_t)row0 * KDIM + col;
      Cp[0 * KDIM] = acc[a][b][0];
      Cp[1 * KDIM] = acc[a][b][1];
      Cp[2 * KDIM] = acc[a][b][2];
      Cp[3 * KDIM] = acc[a][b][3];
    }
  }
}

// ---------------------------------------------------------------------------
// Per-sample rank-1 correction, in place on d_out.
// __syncthreads required: all threads read gt=out[b][t] before the wave
// owning index t overwrites it.
// ---------------------------------------------------------------------------
__global__ __launch_bounds__(256) void correction_k(
    const float* __restrict__ z, const int* __restrict__ tgt,
    const int* __restrict__ var, const float* __restrict__ means,
    const float* __restrict__ lsc, const float* __restrict__ MT,
    float* __restrict__ out) {
  const int b = blockIdx.x;
  const int t = tgt[b];
  if (t < 0) return;
  const int v = var[b];
  const float mval = means[t * VDIM + v];
  const float sval = expf(lsc[t * VDIM + v]);
  const float zv = z[(size_t)b * KDIM + t];
  const float gt = out[(size_t)b * KDIM + t];
  const float coef = (mval + sval * zv) - gt;
  __syncthreads();
  const int i = threadIdx.x * 4;
  float4 g = *(float4*)(out + (size_t)b * KDIM + i);
  float4 mt = *(const float4*)(MT + (size_t)t * KDIM + i);
  g.x += coef * mt.x;
  g.y += coef * mt.y;
  g.z += coef * mt.z;
  g.w += coef * mt.w;
  *(float4*)(out + (size_t)b * KDIM + i) = g;
}

// ---------------------------------------------------------------------------
extern "C" void kernel_launch(void* const* d_in, const int* in_sizes, int n_in,
                              void* d_out, int out_size, void* d_ws,
                              size_t ws_size, hipStream_t stream) {
  const float* z = (const float*)d_in[0];
  const int* tgt = (const int*)d_in[1];
  const int* var = (const int*)d_in[2];
  const float* A = (const float*)d_in[3];
  const float* means = (const float*)d_in[4];
  const float* lsc = (const float*)d_in[5];
  float* out = (float*)d_out;

  const size_t MT_BYTES = (size_t)KDIM * KDIM * 4;   // 4 MB
  const size_t SCR_BYTES = (size_t)2 * 1024 * 1024;  // 2 MB (scr, reused as Mbf)
  float* MT = (float*)d_ws;
  float* scr = (float*)((char*)d_ws + MT_BYTES);
  unsigned short* Mbf = (unsigned short*)scr;
  unsigned short* Zbf = (unsigned short*)((char*)d_ws + MT_BYTES + SCR_BYTES);
  const int use_zbf =
      ws_size >= MT_BYTES + SCR_BYTES + (size_t)BDIM * KDIM * 2 ? 1 : 0;

  hipLaunchKernelGGL(prep, dim3(512), dim3(256), 0, stream, A, MT, scr, z, Zbf,
                     use_zbf);
  hipLaunchKernelGGL(comb_lv0, dim3(8), dim3(256), 0, stream, A, MT);
  hipLaunchKernelGGL(comb_lv1, dim3(8), dim3(256), 0, stream, A, MT);
  hipLaunchKernelGGL(comb_p, dim3(128), dim3(256), 0, stream, A, MT,
                     scr + SCR_L3, 256);
  hipLaunchKernelGGL(comb_q, dim3(128), dim3(256), 0, stream, MT, scr + SCR_L3,
                     256);
  hipLaunchKernelGGL(comb_p, dim3(512), dim3(256), 0, stream, A, MT,
                     scr + SCR_L4, 512);
  hipLaunchKernelGGL(comb_q, dim3(512), dim3(256), 0, stream, MT, scr + SCR_L4,
                     512);
  hipLaunchKernelGGL(mt2bf, dim3(NBLK * NBLK), dim3(256), 0, stream, MT, Mbf);
  if (use_zbf)
    hipLaunchKernelGGL((gemm_mfma<1>), dim3((BDIM / 128) * (KDIM / 128)),
                       dim3(256), 0, stream, z, Zbf, Mbf, out);
  else
    hipLaunchKernelGGL((gemm_mfma<0>), dim3((BDIM / 128) * (KDIM / 128)),
                       dim3(256), 0, stream, z, Zbf, Mbf, out);
  hipLaunchKernelGGL(correction_k, dim3(BDIM), dim3(256), 0, stream, z, tgt,
                     var, means, lsc, MT, out);
}

// Round 3
// 262.888 us; speedup vs baseline: 3.0832x; 1.0694x over previous
//
#include <hip/hip_runtime.h>
#include <hip/hip_bf16.h>
#include <cstdint>

#define KDIM 1024
#define BDIM 8192
#define VDIM 2
#define NBLK 16  // KDIM / 64

typedef __attribute__((ext_vector_type(8))) short short8;
typedef __attribute__((ext_vector_type(4))) float f32x4;

__device__ inline unsigned short f2bf(float x) {
  unsigned u = __builtin_bit_cast(unsigned, x);
  u = (u + 0x7FFFu + ((u >> 16) & 1u)) >> 16;
  return (unsigned short)u;
}

// ---------------------------------------------------------------------------
// Workspace layout (bytes from d_ws):
//   MT   @ 0        4 MB fp32   M^T (column-major M); block-upper-triangular
//   Mbf  @ 4 MB     2 MB bf16   M row-major (Mbf[i][k] = M[i][k])
//   Pt2  @ 6 MB     0.5 MB      lv2 P scratch (2 x 256x256 fp32)
//   Pt3  @ 6.5 MB   1 MB        lv3 P scratch (512x512 fp32)
//   Zbf  @ 7.5 MB   16 MB       Z in bf16
// ---------------------------------------------------------------------------

// --------------------------- shared tile helpers ---------------------------
// STAGE_T: DST[k][m] = SRC[(ROW0+m)*LD + COL0 + k]   (contraction over cols)
#define STAGE_T(DST, SRC, ROW0, COL0, LD)                                   \
  {                                                                         \
    const float* _s = (SRC);                                                \
    _Pragma("unroll") for (int _p = 0; _p < 4; ++_p) {                      \
      const int _m = _p * 16 + rw;                                          \
      float4 _v = *(const float4*)(_s + (size_t)((ROW0) + _m) * (LD) +      \
                                   (COL0) + 4 * k4);                        \
      (DST)[4 * k4 + 0][_m] = _v.x;                                         \
      (DST)[4 * k4 + 1][_m] = _v.y;                                         \
      (DST)[4 * k4 + 2][_m] = _v.z;                                         \
      (DST)[4 * k4 + 3][_m] = _v.w;                                         \
    }                                                                       \
  }

// STAGE_D: DST[k][n] = SRC[(ROW0+k)*LD + COL0 + n]   (contraction over rows)
#define STAGE_D(DST, SRC, ROW0, COL0, LD)                                   \
  {                                                                         \
    const float* _s = (SRC);                                                \
    _Pragma("unroll") for (int _p = 0; _p < 4; ++_p) {                      \
      const int _kk = _p * 16 + rw;                                         \
      *(float4*)&(DST)[_kk][4 * k4] =                                       \
          *(const float4*)(_s + (size_t)((ROW0) + _kk) * (LD) + (COL0) +    \
                           4 * k4);                                         \
    }                                                                       \
  }

#define ZERO_ACC                                                            \
  _Pragma("unroll") for (int _a = 0; _a < 4; ++_a)                          \
      _Pragma("unroll") for (int _b = 0; _b < 4; ++_b) acc[_a][_b] = 0.f;

// acc[a][b] += sum_k Ls[k][4tm+a] * Rs[k][4tn+b]
__device__ __forceinline__ void mac64(const float (*Ls)[68],
                                      const float (*Rs)[68], int tm, int tn,
                                      float acc[4][4]) {
#pragma unroll 4
  for (int k = 0; k < 64; ++k) {
    const float4 av = *(const float4*)&Ls[k][4 * tm];
    const float4 bv = *(const float4*)&Rs[k][4 * tn];
    const float aa[4] = {av.x, av.y, av.z, av.w};
    const float bb4[4] = {bv.x, bv.y, bv.z, bv.w};
#pragma unroll
    for (int a = 0; a < 4; ++a)
#pragma unroll
      for (int b = 0; b < 4; ++b) acc[a][b] += aa[a] * bb4[b];
  }
}

// Store acc tile (rows R0+4tm+a, cols C0+4tn+b) to MT (fp32, float4).
#define STORE_MT(R0, C0)                                                    \
  _Pragma("unroll") for (int _a = 0; _a < 4; ++_a) {                        \
    *(float4*)(MT + (size_t)((R0) + 4 * tm + _a) * KDIM + (C0) + 4 * tn) =  \
        make_float4(acc[_a][0], acc[_a][1], acc[_a][2], acc[_a][3]);        \
  }

// Write the transposed bf16 mirror: Mbf[(C0+r)][(R0+j)] = tile[j][r],
// bounced through LDS buffer BUF for coalesced ushort4 stores.
#define MBF_TILE(R0, C0, BUF)                                               \
  {                                                                         \
    __syncthreads();                                                        \
    _Pragma("unroll") for (int _a = 0; _a < 4; ++_a)                        \
        _Pragma("unroll") for (int _b = 0; _b < 4; ++_b)                    \
            (BUF)[4 * tm + _a][4 * tn + _b] = acc[_a][_b];                  \
    __syncthreads();                                                        \
    const int _tr = tid >> 4, _tc = tid & 15;                               \
    _Pragma("unroll") for (int _p = 0; _p < 4; ++_p) {                      \
      const int _il = _p * 16 + _tr;                                        \
      ushort4 _o;                                                           \
      _o.x = f2bf((BUF)[4 * _tc + 0][_il]);                                 \
      _o.y = f2bf((BUF)[4 * _tc + 1][_il]);                                 \
      _o.z = f2bf((BUF)[4 * _tc + 2][_il]);                                 \
      _o.w = f2bf((BUF)[4 * _tc + 3][_il]);                                 \
      *(ushort4*)(Mbf + (size_t)((C0) + _il) * KDIM + (R0) + 4 * _tc) = _o; \
    }                                                                       \
  }

// ---------------------------------------------------------------------------
// prep: blocks 0..15 invert the 16 diagonal 64x64 unit-lower-tri blocks of
// (I - A): write column c of T into MT row (64ib+c) AND the bf16 mirror
// into Mbf. Blocks 16+: zero all off-diagonal 64-blocks of MT (lower zeros
// are read by correction; upper are overwritten later) and of Mbf (upper
// zeros read by gemm), and convert Z -> bf16. No scratch zero: P kernels
// now plain-store.
// ---------------------------------------------------------------------------
__global__ __launch_bounds__(256) void prep(const float* __restrict__ A,
                                            float* __restrict__ MT,
                                            unsigned short* __restrict__ Mbf,
                                            const float* __restrict__ Z,
                                            unsigned short* __restrict__ Zbf,
                                            int do_zbf) {
  __shared__ float As[64 * 64];
  const int bid = blockIdx.x;

  if (bid < NBLK) {
    const int base = bid * 64;
    for (int i = threadIdx.x; i < 64 * 64; i += 256)
      As[i] = A[(size_t)(base + (i >> 6)) * KDIM + base + (i & 63)];
    __syncthreads();
    if (threadIdx.x < 64) {
      const int c = threadIdx.x;
      float m[64];
#pragma unroll
      for (int r = 0; r < 64; ++r) m[r] = (r == c) ? 1.f : 0.f;
#pragma unroll
      for (int r = 1; r < 64; ++r) {
        float acc0 = 0.f, acc1 = 0.f;
#pragma unroll
        for (int i = 0; i < 64; ++i) {
          if (i >= r) break;
          if (i & 1) acc1 += As[r * 64 + i] * m[i];
          else       acc0 += As[r * 64 + i] * m[i];
        }
        const float v = acc0 + acc1;
        m[r] = (r > c) ? v : m[r];
      }
#pragma unroll
      for (int r = 0; r < 64; r += 4) {
        float4 v = make_float4(m[r], m[r + 1], m[r + 2], m[r + 3]);
        *(float4*)(MT + (size_t)(base + c) * KDIM + base + r) = v;
      }
      // bf16 mirror: Mbf[base+r][base+c] = T[r][c] (coalesced across c)
#pragma unroll
      for (int r = 0; r < 64; ++r)
        Mbf[(size_t)(base + r) * KDIM + base + c] = f2bf(m[r]);
    }
    return;
  }

  const int wid = bid - NBLK;
  const int nw = gridDim.x - NBLK;
  const int idx0 = wid * 256 + threadIdx.x;
  const int stride = nw * 256;
  const float4 z4 = make_float4(0.f, 0.f, 0.f, 0.f);

  // MT off-diagonal zero: 240 blocks x 1024 float4
  for (int i = idx0; i < 240 * 1024; i += stride) {
    const int blk = i >> 10, off = i & 1023;
    const int bi = blk / 15;
    int bj = blk % 15;
    bj += (bj >= bi);
    *(float4*)(MT + (size_t)(bi * 64 + (off >> 4)) * KDIM + bj * 64 +
               4 * (off & 15)) = z4;
  }
  // Mbf off-diagonal zero: 240 blocks x 512 uint4 (64 rows x 8 uint4)
  const uint4 u4 = make_uint4(0u, 0u, 0u, 0u);
  for (int i = idx0; i < 240 * 512; i += stride) {
    const int blk = i >> 9, off = i & 511;
    const int bi = blk / 15;
    int bj = blk % 15;
    bj += (bj >= bi);
    *(uint4*)(Mbf + (size_t)(bi * 64 + (off >> 3)) * KDIM + bj * 64 +
              8 * (off & 7)) = u4;
  }
  // Z -> bf16
  if (do_zbf) {
    for (int i = idx0; i < BDIM * KDIM / 4; i += stride) {
      float4 v = *(const float4*)(Z + 4 * (size_t)i);
      ushort4 o;
      o.x = f2bf(v.x);
      o.y = f2bf(v.y);
      o.z = f2bf(v.z);
      o.w = f2bf(v.w);
      *(ushort4*)(Zbf + 4 * (size_t)i) = o;
    }
  }
}

// ---------------------------------------------------------------------------
// comb01: merged levels h=64 and h=128 for one 256-superblock.
// Grid 16 = 4 superblocks x (jt,rt) in {0,1}^2. Each block recomputes the
// lv0 64x64 tiles it needs locally in LDS (no cross-block deps), then
// computes the lv1 Q tile (jt,rt) directly. Designated blocks also write
// the lv0 tiles to MT/Mbf. Max 10 tile-MACs per block.
// ---------------------------------------------------------------------------
__global__ __launch_bounds__(256) void comb01(const float* __restrict__ A,
                                              float* __restrict__ MT,
                                              unsigned short* __restrict__ Mbf) {
  int b = blockIdx.x;
  const int rt = b & 1;
  const int jt = (b >> 1) & 1;
  const int s = b >> 2;
  const int base = s * 256;

  __shared__ float Ls[64][68];
  __shared__ float Rs[64][68];
  __shared__ float tQ0L[64][68];  // lv0-low Q, Ls-format (tQ0L[r][j])
  __shared__ float tQ0H[64][68];  // lv0-high Q, direct format (tQ0H[j][r])
  __shared__ float tP0[64][68];   // P(jt,0), LsP-format
  __shared__ float tP1[64][68];   // P(jt,1), LsP-format

  const int tid = threadIdx.x;
  const int k4 = tid & 15;
  const int rw = tid >> 4;
  const int tm = tid >> 4;
  const int tn = tid & 15;
  float acc[4][4];

  if (jt == 0) {
    // lv0 low pair (64-blocks 4s,4s+1): P_low then Q0L
    STAGE_T(Ls, MT, base, base, KDIM);        // T_{4s}
    STAGE_T(Rs, A, base + 64, base, KDIM);    // A21 low
    __syncthreads();
    ZERO_ACC;
    mac64(Ls, Rs, tm, tn, acc);
    __syncthreads();
#pragma unroll
    for (int a = 0; a < 4; ++a)
#pragma unroll
      for (int b2 = 0; b2 < 4; ++b2) tP0[4 * tn + b2][4 * tm + a] = acc[a][b2];
    STAGE_D(Rs, MT, base + 64, base + 64, KDIM);  // T_{4s+1}
    __syncthreads();
    ZERO_ACC;
    mac64(tP0, Rs, tm, tn, acc);
    __syncthreads();
#pragma unroll
    for (int a = 0; a < 4; ++a)
#pragma unroll
      for (int b2 = 0; b2 < 4; ++b2) tQ0L[4 * tn + b2][4 * tm + a] = acc[a][b2];
    if (rt == 0) {
      STORE_MT(base, base + 64);
      MBF_TILE(base, base + 64, Rs);
    }
  }
  __syncthreads();

  if (rt == 1) {
    // lv0 high pair (64-blocks 4s+2,4s+3): P_high then Q0H
    STAGE_T(Ls, MT, base + 128, base + 128, KDIM);  // T_{4s+2}
    STAGE_T(Rs, A, base + 192, base + 128, KDIM);   // A21 high
    __syncthreads();
    ZERO_ACC;
    mac64(Ls, Rs, tm, tn, acc);
    __syncthreads();
#pragma unroll
    for (int a = 0; a < 4; ++a)
#pragma unroll
      for (int b2 = 0; b2 < 4; ++b2) tP1[4 * tn + b2][4 * tm + a] = acc[a][b2];
    STAGE_D(Rs, MT, base + 192, base + 192, KDIM);  // T_{4s+3}
    __syncthreads();
    ZERO_ACC;
    mac64(tP1, Rs, tm, tn, acc);
    __syncthreads();
#pragma unroll
    for (int a = 0; a < 4; ++a)
#pragma unroll
      for (int b2 = 0; b2 < 4; ++b2) tQ0H[4 * tm + a][4 * tn + b2] = acc[a][b2];
    if (jt == 1) {
      STORE_MT(base + 128, base + 192);
      MBF_TILE(base + 128, base + 192, Rs);
    }
  }
  __syncthreads();

  // lv1 P tiles: P(jt, kb2) for kb2 <= rt; contraction kb in [jt,2)
  STAGE_T(Ls, MT, base + 64 * jt, base + 64 * jt, KDIM);  // T_{4s+jt}
  __syncthreads();
  for (int kb2 = 0; kb2 <= rt; ++kb2) {
    ZERO_ACC;
    for (int kb = jt; kb < 2; ++kb) {
      STAGE_T(Rs, A, base + 128 + 64 * kb2, base + 64 * kb, KDIM);
      __syncthreads();
      mac64(kb == jt ? Ls : tQ0L, Rs, tm, tn, acc);
      __syncthreads();
    }
    if (kb2 == 0) {
#pragma unroll
      for (int a = 0; a < 4; ++a)
#pragma unroll
        for (int b2 = 0; b2 < 4; ++b2) tP0[4 * tn + b2][4 * tm + a] = acc[a][b2];
    } else {
#pragma unroll
      for (int a = 0; a < 4; ++a)
#pragma unroll
        for (int b2 = 0; b2 < 4; ++b2) tP1[4 * tn + b2][4 * tm + a] = acc[a][b2];
    }
  }
  __syncthreads();

  // lv1 Q(jt,rt) = sum_{kb2<=rt} P(jt,kb2) * M22^T(kb2,rt)
  ZERO_ACC;
  if (rt == 0) {
    STAGE_D(Rs, MT, base + 128, base + 128, KDIM);  // T_{4s+2}
    __syncthreads();
    mac64(tP0, Rs, tm, tn, acc);
    __syncthreads();
  } else {
    mac64(tP0, tQ0H, tm, tn, acc);  // RsM(0,1) = Q0H (local)
    __syncthreads();
    STAGE_D(Rs, MT, base + 192, base + 192, KDIM);  // T_{4s+3}
    __syncthreads();
    mac64(tP1, Rs, tm, tn, acc);
    __syncthreads();
  }
  STORE_MT(base + 64 * jt, base + 128 + 64 * rt);
  MBF_TILE(base + 64 * jt, base + 128 + 64 * rt, Rs);
}

// ---------------------------------------------------------------------------
// Levels 2/3: P and Q kernels with internal K-contraction (no atomics,
// no scratch zeroing), exploiting block-triangular structure.
// p_k<T>: P(jb,rb) = sum_{kb in [jb,T)} M11^T(jb,kb) x A21(rb,kb)
// q_k<T>: Q(jb,rb) = sum_{kb in [0,rb]} P(jb,kb) x M22^T(kb,rb);
//         writes final MT tile + transposed bf16 Mbf tile.
// ---------------------------------------------------------------------------
template <int T>
__global__ __launch_bounds__(256) void p_k(const float* __restrict__ A,
                                           const float* __restrict__ MT,
                                           float* __restrict__ Pt) {
  int b = blockIdx.x;
  const int rb = b % T; b /= T;
  const int jb = b % T; b /= T;
  const int c = b;
  const int h = 64 * T;
  const int base = c * 2 * h;

  __shared__ float Ls[64][68];
  __shared__ float Rs[64][68];
  const int tid = threadIdx.x;
  const int k4 = tid & 15;
  const int rw = tid >> 4;
  const int tm = tid >> 4;
  const int tn = tid & 15;
  float acc[4][4];
  ZERO_ACC;

  for (int kb = jb; kb < T; ++kb) {
    STAGE_T(Ls, MT, base + 64 * jb, base + 64 * kb, KDIM);
    STAGE_T(Rs, A, base + h + 64 * rb, base + 64 * kb, KDIM);
    __syncthreads();
    mac64(Ls, Rs, tm, tn, acc);
    __syncthreads();
  }

  float* P0 = Pt + (size_t)c * h * h;
#pragma unroll
  for (int a = 0; a < 4; ++a)
    *(float4*)(P0 + (size_t)(64 * jb + 4 * tm + a) * h + 64 * rb + 4 * tn) =
        make_float4(acc[a][0], acc[a][1], acc[a][2], acc[a][3]);
}

template <int T>
__global__ __launch_bounds__(256) void q_k(float* __restrict__ MT,
                                           const float* __restrict__ Pt,
                                           unsigned short* __restrict__ Mbf) {
  int b = blockIdx.x;
  const int rb = b % T; b /= T;
  const int jb = b % T; b /= T;
  const int c = b;
  const int h = 64 * T;
  const int base = c * 2 * h;

  __shared__ float Ls[64][68];
  __shared__ float Rs[64][68];
  const int tid = threadIdx.x;
  const int k4 = tid & 15;
  const int rw = tid >> 4;
  const int tm = tid >> 4;
  const int tn = tid & 15;
  float acc[4][4];
  ZERO_ACC;

  const float* P0 = Pt + (size_t)c * h * h;
  for (int kb = 0; kb <= rb; ++kb) {
    STAGE_T(Ls, P0, 64 * jb, 64 * kb, h);
    STAGE_D(Rs, MT, base + h + 64 * kb, base + h + 64 * rb, KDIM);
    __syncthreads();
    mac64(Ls, Rs, tm, tn, acc);
    __syncthreads();
  }

  STORE_MT(base + 64 * jb, base + h + 64 * rb);
  MBF_TILE(base + 64 * jb, base + h + 64 * rb, Ls);
}

// ---------------------------------------------------------------------------
// bf16 MFMA GEMM.  C[b][i] = sum_k Z[b][k] * Mbf[i][k]   (NT)
// 128x128 tile, 4 waves (2x2 of 64x64), BK=64, mfma_f32_16x16x32_bf16.
// Decode: d%8 = xb%8 (XCD-local Z panel); xb bit-5 flips ni so the CU pair
// (d, d+256) sums to constant 18 K-units.
// ---------------------------------------------------------------------------
#define LDB 72

template <int ZBF>
__global__ __launch_bounds__(256) void gemm_mfma(
    const float* __restrict__ Z, const unsigned short* __restrict__ Zbf,
    const unsigned short* __restrict__ Mbf, float* __restrict__ C) {
  __shared__ unsigned short As[128][LDB];
  __shared__ unsigned short Bs[128][LDB];

  const int d = blockIdx.x;
  const int xbl = d & 7;
  const int nir = (d >> 3) & 7;
  const int xbh = d >> 6;
  const int xb = xbh * 8 + xbl;
  const int ni = (xb & 32) ? (7 - nir) : nir;
  const int b0 = xb * 128;
  const int i0 = ni * 128;

  const int tid = threadIdx.x;
  const int w = tid >> 6;
  const int lane = tid & 63;
  const int wr = w >> 1, wc = w & 1;
  const int mlane = lane & 15;
  const int q = lane >> 4;

  const int rq = tid >> 4, kq = tid & 15;
  const int cb = tid >> 3, ck = tid & 7;

  f32x4 acc[4][4];
#pragma unroll
  for (int a = 0; a < 4; ++a)
#pragma unroll
    for (int b = 0; b < 4; ++b) acc[a][b] = (f32x4){0.f, 0.f, 0.f, 0.f};

  const int nkb = 2 * (ni + 1);
  for (int kb = 0; kb < nkb; ++kb) {
    const int k0 = kb * 64;
    if (ZBF) {
#pragma unroll
      for (int p = 0; p < 4; ++p) {
        const int r = p * 32 + cb;
        *(uint4*)&As[r][8 * ck] =
            *(const uint4*)(Zbf + (size_t)(b0 + r) * KDIM + k0 + 8 * ck);
      }
    } else {
#pragma unroll
      for (int p = 0; p < 8; ++p) {
        const int r = p * 16 + rq;
        float4 zv = *(const float4*)(Z + (size_t)(b0 + r) * KDIM + k0 + 4 * kq);
        ushort4 o;
        o.x = f2bf(zv.x);
        o.y = f2bf(zv.y);
        o.z = f2bf(zv.z);
        o.w = f2bf(zv.w);
        *(ushort4*)&As[r][4 * kq] = o;
      }
    }
#pragma unroll
    for (int p = 0; p < 4; ++p) {
      const int c = p * 32 + cb;
      *(uint4*)&Bs[c][8 * ck] =
          *(const uint4*)(Mbf + (size_t)(i0 + c) * KDIM + k0 + 8 * ck);
    }
    __syncthreads();
#pragma unroll
    for (int ks = 0; ks < 2; ++ks) {
      const int kf = ks * 32 + q * 8;
      short8 av[4], bv[4];
#pragma unroll
      for (int a = 0; a < 4; ++a)
        av[a] = *(const short8*)&As[wr * 64 + 16 * a + mlane][kf];
#pragma unroll
      for (int b = 0; b < 4; ++b)
        bv[b] = *(const short8*)&Bs[wc * 64 + 16 * b + mlane][kf];
#pragma unroll
      for (int a = 0; a < 4; ++a)
#pragma unroll
        for (int b = 0; b < 4; ++b)
          acc[a][b] =
              __builtin_amdgcn_mfma_f32_16x16x32_bf16(av[a], bv[b], acc[a][b], 0, 0, 0);
    }
    __syncthreads();
  }

#pragma unroll
  for (int a = 0; a < 4; ++a) {
    const int row0 = b0 + wr * 64 + 16 * a + q * 4;
#pragma unroll
    for (int b = 0; b < 4; ++b) {
      const int col = i0 + wc * 64 + 16 * b + mlane;
      float* Cp = C + (size_t)row0 * KDIM + col;
      Cp[0 * KDIM] = acc[a][b][0];
      Cp[1 * KDIM] = acc[a][b][1];
      Cp[2 * KDIM] = acc[a][b][2];
      Cp[3 * KDIM] = acc[a][b][3];
    }
  }
}

// ---------------------------------------------------------------------------
// Per-sample rank-1 correction, in place on d_out.
// __syncthreads required: all threads read gt=out[b][t] before the wave
// owning index t overwrites it.
// ---------------------------------------------------------------------------
__global__ __launch_bounds__(256) void correction_k(
    const float* __restrict__ z, const int* __restrict__ tgt,
    const int* __restrict__ var, const float* __restrict__ means,
    const float* __restrict__ lsc, const float* __restrict__ MT,
    float* __restrict__ out) {
  const int b = blockIdx.x;
  const int t = tgt[b];
  if (t < 0) return;
  const int v = var[b];
  const float mval = means[t * VDIM + v];
  const float sval = expf(lsc[t * VDIM + v]);
  const float zv = z[(size_t)b * KDIM + t];
  const float gt = out[(size_t)b * KDIM + t];
  const float coef = (mval + sval * zv) - gt;
  __syncthreads();
  const int i = threadIdx.x * 4;
  float4 g = *(float4*)(out + (size_t)b * KDIM + i);
  float4 mt = *(const float4*)(MT + (size_t)t * KDIM + i);
  g.x += coef * mt.x;
  g.y += coef * mt.y;
  g.z += coef * mt.z;
  g.w += coef * mt.w;
  *(float4*)(out + (size_t)b * KDIM + i) = g;
}

// ---------------------------------------------------------------------------
extern "C" void kernel_launch(void* const* d_in, const int* in_sizes, int n_in,
                              void* d_out, int out_size, void* d_ws,
                              size_t ws_size, hipStream_t stream) {
  const float* z = (const float*)d_in[0];
  const int* tgt = (const int*)d_in[1];
  const int* var = (const int*)d_in[2];
  const float* A = (const float*)d_in[3];
  const float* means = (const float*)d_in[4];
  const float* lsc = (const float*)d_in[5];
  float* out = (float*)d_out;

  char* ws = (char*)d_ws;
  float* MT = (float*)ws;                                       // 4 MB
  unsigned short* Mbf = (unsigned short*)(ws + (4u << 20));     // 2 MB
  float* Pt2 = (float*)(ws + (6u << 20));                       // 0.5 MB
  float* Pt3 = (float*)(ws + (6u << 20) + (512u << 10));        // 1 MB
  unsigned short* Zbf = (unsigned short*)(ws + (7u << 20) + (512u << 10));
  const int use_zbf =
      ws_size >= (7u << 20) + (512u << 10) + (size_t)BDIM * KDIM * 2 ? 1 : 0;

  hipLaunchKernelGGL(prep, dim3(512), dim3(256), 0, stream, A, MT, Mbf, z, Zbf,
                     use_zbf);
  hipLaunchKernelGGL(comb01, dim3(16), dim3(256), 0, stream, A, MT, Mbf);
  hipLaunchKernelGGL((p_k<4>), dim3(32), dim3(256), 0, stream, A, MT, Pt2);
  hipLaunchKernelGGL((q_k<4>), dim3(32), dim3(256), 0, stream, MT, Pt2, Mbf);
  hipLaunchKernelGGL((p_k<8>), dim3(64), dim3(256), 0, stream, A, MT, Pt3);
  hipLaunchKernelGGL((q_k<8>), dim3(64), dim3(256), 0, stream, MT, Pt3, Mbf);
  if (use_zbf)
    hipLaunchKernelGGL((gemm_mfma<1>), dim3((BDIM / 128) * (KDIM / 128)),
                       dim3(256), 0, stream, z, Zbf, Mbf, out);
  else
    hipLaunchKernelGGL((gemm_mfma<0>), dim3((BDIM / 128) * (KDIM / 128)),
                       dim3(256), 0, stream, z, Zbf, Mbf, out);
  hipLaunchKernelGGL(correction_k, dim3(BDIM), dim3(256), 0, stream, z, tgt,
                     var, means, lsc, MT, out);
}

// Round 4
// 256.472 us; speedup vs baseline: 3.1603x; 1.0250x over previous
//
#include <hip/hip_runtime.h>
#include <hip/hip_bf16.h>
#include <cstdint>

#define KDIM 1024
#define BDIM 8192
#define VDIM 2
#define NBLK 16  // KDIM / 64

typedef __attribute__((ext_vector_type(8))) short short8;
typedef __attribute__((ext_vector_type(4))) float f32x4;

__device__ inline unsigned short f2bf(float x) {
  unsigned u = __builtin_bit_cast(unsigned, x);
  u = (u + 0x7FFFu + ((u >> 16) & 1u)) >> 16;
  return (unsigned short)u;
}

__device__ inline float bf2f(unsigned short x) {
  return __builtin_bit_cast(float, (unsigned)x << 16);
}

// ---------------------------------------------------------------------------
// Workspace layout (bytes from d_ws):
//   MT   @ 0        4 MB fp32   M^T (MT[t][i] = M[i][t])
//   Mbf  @ 4 MB     2 MB bf16   M row-major (Mbf[i][k] = M[i][k])
//   Pt2  @ 6 MB     0.5 MB      lv2 P scratch
//   Pt3  @ 6.5 MB   1 MB        lv3 P scratch
//   Zbf  @ 7.5 MB   16 MB       Z in bf16
// ---------------------------------------------------------------------------

// --------------------------- shared tile helpers ---------------------------
#define STAGE_T(DST, SRC, ROW0, COL0, LD)                                   \
  {                                                                         \
    const float* _s = (SRC);                                                \
    _Pragma("unroll") for (int _p = 0; _p < 4; ++_p) {                      \
      const int _m = _p * 16 + rw;                                          \
      float4 _v = *(const float4*)(_s + (size_t)((ROW0) + _m) * (LD) +      \
                                   (COL0) + 4 * k4);                        \
      (DST)[4 * k4 + 0][_m] = _v.x;                                         \
      (DST)[4 * k4 + 1][_m] = _v.y;                                         \
      (DST)[4 * k4 + 2][_m] = _v.z;                                         \
      (DST)[4 * k4 + 3][_m] = _v.w;                                         \
    }                                                                       \
  }

#define STAGE_D(DST, SRC, ROW0, COL0, LD)                                   \
  {                                                                         \
    const float* _s = (SRC);                                                \
    _Pragma("unroll") for (int _p = 0; _p < 4; ++_p) {                      \
      const int _kk = _p * 16 + rw;                                         \
      *(float4*)&(DST)[_kk][4 * k4] =                                       \
          *(const float4*)(_s + (size_t)((ROW0) + _kk) * (LD) + (COL0) +    \
                           4 * k4);                                         \
    }                                                                       \
  }

#define ZERO_ACC                                                            \
  _Pragma("unroll") for (int _a = 0; _a < 4; ++_a)                          \
      _Pragma("unroll") for (int _b = 0; _b < 4; ++_b) acc[_a][_b] = 0.f;

__device__ __forceinline__ void mac64(const float (*Ls)[68],
                                      const float (*Rs)[68], int tm, int tn,
                                      float acc[4][4]) {
#pragma unroll 4
  for (int k = 0; k < 64; ++k) {
    const float4 av = *(const float4*)&Ls[k][4 * tm];
    const float4 bv = *(const float4*)&Rs[k][4 * tn];
    const float aa[4] = {av.x, av.y, av.z, av.w};
    const float bb4[4] = {bv.x, bv.y, bv.z, bv.w};
#pragma unroll
    for (int a = 0; a < 4; ++a)
#pragma unroll
      for (int b = 0; b < 4; ++b) acc[a][b] += aa[a] * bb4[b];
  }
}

#define STORE_MT(R0, C0)                                                    \
  _Pragma("unroll") for (int _a = 0; _a < 4; ++_a) {                        \
    *(float4*)(MT + (size_t)((R0) + 4 * tm + _a) * KDIM + (C0) + 4 * tn) =  \
        make_float4(acc[_a][0], acc[_a][1], acc[_a][2], acc[_a][3]);        \
  }

#define MBF_TILE(R0, C0, BUF)                                               \
  {                                                                         \
    __syncthreads();                                                        \
    _Pragma("unroll") for (int _a = 0; _a < 4; ++_a)                        \
        _Pragma("unroll") for (int _b = 0; _b < 4; ++_b)                    \
            (BUF)[4 * tm + _a][4 * tn + _b] = acc[_a][_b];                  \
    __syncthreads();                                                        \
    const int _tr = tid >> 4, _tc = tid & 15;                               \
    _Pragma("unroll") for (int _p = 0; _p < 4; ++_p) {                      \
      const int _il = _p * 16 + _tr;                                        \
      ushort4 _o;                                                           \
      _o.x = f2bf((BUF)[4 * _tc + 0][_il]);                                 \
      _o.y = f2bf((BUF)[4 * _tc + 1][_il]);                                 \
      _o.z = f2bf((BUF)[4 * _tc + 2][_il]);                                 \
      _o.w = f2bf((BUF)[4 * _tc + 3][_il]);                                 \
      *(ushort4*)(Mbf + (size_t)((C0) + _il) * KDIM + (R0) + 4 * _tc) = _o; \
    }                                                                       \
  }

// ---------------------------------------------------------------------------
// prep_inv: invert the 16 diagonal 64x64 unit-lower-tri blocks of (I - A).
// Writes column c of T into MT row (64ib+c) AND the bf16 mirror into Mbf.
// (zeroing + Z->bf16 moved into p4_stream's idle blocks.)
// ---------------------------------------------------------------------------
__global__ __launch_bounds__(256) void prep_inv(const float* __restrict__ A,
                                                float* __restrict__ MT,
                                                unsigned short* __restrict__ Mbf) {
  __shared__ float As[64 * 64];
  const int base = blockIdx.x * 64;
  for (int i = threadIdx.x; i < 64 * 64; i += 256)
    As[i] = A[(size_t)(base + (i >> 6)) * KDIM + base + (i & 63)];
  __syncthreads();
  if (threadIdx.x < 64) {
    const int c = threadIdx.x;
    float m[64];
#pragma unroll
    for (int r = 0; r < 64; ++r) m[r] = (r == c) ? 1.f : 0.f;
#pragma unroll
    for (int r = 1; r < 64; ++r) {
      float acc0 = 0.f, acc1 = 0.f;
#pragma unroll
      for (int i = 0; i < 64; ++i) {
        if (i >= r) break;
        if (i & 1) acc1 += As[r * 64 + i] * m[i];
        else       acc0 += As[r * 64 + i] * m[i];
      }
      const float v = acc0 + acc1;
      m[r] = (r > c) ? v : m[r];
    }
#pragma unroll
    for (int r = 0; r < 64; r += 4) {
      float4 v = make_float4(m[r], m[r + 1], m[r + 2], m[r + 3]);
      *(float4*)(MT + (size_t)(base + c) * KDIM + base + r) = v;
    }
#pragma unroll
    for (int r = 0; r < 64; ++r)
      Mbf[(size_t)(base + r) * KDIM + base + c] = f2bf(m[r]);
  }
}

// ---------------------------------------------------------------------------
// comb01: merged levels h=64 and h=128 (verified round 3, unchanged).
// ---------------------------------------------------------------------------
__global__ __launch_bounds__(256) void comb01(const float* __restrict__ A,
                                              float* __restrict__ MT,
                                              unsigned short* __restrict__ Mbf) {
  int b = blockIdx.x;
  const int rt = b & 1;
  const int jt = (b >> 1) & 1;
  const int s = b >> 2;
  const int base = s * 256;

  __shared__ float Ls[64][68];
  __shared__ float Rs[64][68];
  __shared__ float tQ0L[64][68];
  __shared__ float tQ0H[64][68];
  __shared__ float tP0[64][68];
  __shared__ float tP1[64][68];

  const int tid = threadIdx.x;
  const int k4 = tid & 15;
  const int rw = tid >> 4;
  const int tm = tid >> 4;
  const int tn = tid & 15;
  float acc[4][4];

  if (jt == 0) {
    STAGE_T(Ls, MT, base, base, KDIM);
    STAGE_T(Rs, A, base + 64, base, KDIM);
    __syncthreads();
    ZERO_ACC;
    mac64(Ls, Rs, tm, tn, acc);
    __syncthreads();
#pragma unroll
    for (int a = 0; a < 4; ++a)
#pragma unroll
      for (int b2 = 0; b2 < 4; ++b2) tP0[4 * tn + b2][4 * tm + a] = acc[a][b2];
    STAGE_D(Rs, MT, base + 64, base + 64, KDIM);
    __syncthreads();
    ZERO_ACC;
    mac64(tP0, Rs, tm, tn, acc);
    __syncthreads();
#pragma unroll
    for (int a = 0; a < 4; ++a)
#pragma unroll
      for (int b2 = 0; b2 < 4; ++b2) tQ0L[4 * tn + b2][4 * tm + a] = acc[a][b2];
    if (rt == 0) {
      STORE_MT(base, base + 64);
      MBF_TILE(base, base + 64, Rs);
    }
  }
  __syncthreads();

  if (rt == 1) {
    STAGE_T(Ls, MT, base + 128, base + 128, KDIM);
    STAGE_T(Rs, A, base + 192, base + 128, KDIM);
    __syncthreads();
    ZERO_ACC;
    mac64(Ls, Rs, tm, tn, acc);
    __syncthreads();
#pragma unroll
    for (int a = 0; a < 4; ++a)
#pragma unroll
      for (int b2 = 0; b2 < 4; ++b2) tP1[4 * tn + b2][4 * tm + a] = acc[a][b2];
    STAGE_D(Rs, MT, base + 192, base + 192, KDIM);
    __syncthreads();
    ZERO_ACC;
    mac64(tP1, Rs, tm, tn, acc);
    __syncthreads();
#pragma unroll
    for (int a = 0; a < 4; ++a)
#pragma unroll
      for (int b2 = 0; b2 < 4; ++b2) tQ0H[4 * tm + a][4 * tn + b2] = acc[a][b2];
    if (jt == 1) {
      STORE_MT(base + 128, base + 192);
      MBF_TILE(base + 128, base + 192, Rs);
    }
  }
  __syncthreads();

  STAGE_T(Ls, MT, base + 64 * jt, base + 64 * jt, KDIM);
  __syncthreads();
  for (int kb2 = 0; kb2 <= rt; ++kb2) {
    ZERO_ACC;
    for (int kb = jt; kb < 2; ++kb) {
      STAGE_T(Rs, A, base + 128 + 64 * kb2, base + 64 * kb, KDIM);
      __syncthreads();
      mac64(kb == jt ? Ls : tQ0L, Rs, tm, tn, acc);
      __syncthreads();
    }
    if (kb2 == 0) {
#pragma unroll
      for (int a = 0; a < 4; ++a)
#pragma unroll
        for (int b2 = 0; b2 < 4; ++b2) tP0[4 * tn + b2][4 * tm + a] = acc[a][b2];
    } else {
#pragma unroll
      for (int a = 0; a < 4; ++a)
#pragma unroll
        for (int b2 = 0; b2 < 4; ++b2) tP1[4 * tn + b2][4 * tm + a] = acc[a][b2];
    }
  }
  __syncthreads();

  ZERO_ACC;
  if (rt == 0) {
    STAGE_D(Rs, MT, base + 128, base + 128, KDIM);
    __syncthreads();
    mac64(tP0, Rs, tm, tn, acc);
    __syncthreads();
  } else {
    mac64(tP0, tQ0H, tm, tn, acc);
    __syncthreads();
    STAGE_D(Rs, MT, base + 192, base + 192, KDIM);
    __syncthreads();
    mac64(tP1, Rs, tm, tn, acc);
    __syncthreads();
  }
  STORE_MT(base + 64 * jt, base + 128 + 64 * rt);
  MBF_TILE(base + 64 * jt, base + 128 + 64 * rt, Rs);
}

// ---------------------------------------------------------------------------
// p4_stream: blocks 0..31 compute lv2 P tiles (T=4); blocks 32+ do the
// streaming work moved out of prep: zero MT strict-lower blocks (bi>bj,
// read only by the gemm epilogue's MT gather), zero Mbf strict-upper
// blocks (bi<bj, read by the gemm B-stage), and convert Z -> bf16.
// Strictly disjoint from every tile the combine chain writes.
// ---------------------------------------------------------------------------
__global__ __launch_bounds__(256) void p4_stream(
    const float* __restrict__ A, float* __restrict__ MT,
    float* __restrict__ Pt, const float* __restrict__ Z,
    unsigned short* __restrict__ Zbf, unsigned short* __restrict__ Mbf,
    int do_zbf) {
  __shared__ float Ls[64][68];
  __shared__ float Rs[64][68];

  if (blockIdx.x >= 32) {
    const int wid = blockIdx.x - 32;
    const int nw = gridDim.x - 32;
    const int idx0 = wid * 256 + threadIdx.x;
    const int stride = nw * 256;
    const float4 z4 = make_float4(0.f, 0.f, 0.f, 0.f);
    const uint4 u4 = make_uint4(0u, 0u, 0u, 0u);

    for (int i = idx0; i < 256 * 1024; i += stride) {
      const int blk = i >> 10, off = i & 1023;
      const int bi = blk >> 4, bj = blk & 15;
      if (bi <= bj) continue;  // strict-lower MT blocks only
      *(float4*)(MT + (size_t)(bi * 64 + (off >> 4)) * KDIM + bj * 64 +
                 4 * (off & 15)) = z4;
    }
    for (int i = idx0; i < 256 * 512; i += stride) {
      const int blk = i >> 9, off = i & 511;
      const int bi = blk >> 4, bj = blk & 15;
      if (bi >= bj) continue;  // strict-upper Mbf blocks only
      *(uint4*)(Mbf + (size_t)(bi * 64 + (off >> 3)) * KDIM + bj * 64 +
                8 * (off & 7)) = u4;
    }
    if (do_zbf) {
      for (int i = idx0; i < BDIM * KDIM / 4; i += stride) {
        float4 v = *(const float4*)(Z + 4 * (size_t)i);
        ushort4 o;
        o.x = f2bf(v.x);
        o.y = f2bf(v.y);
        o.z = f2bf(v.z);
        o.w = f2bf(v.w);
        *(ushort4*)(Zbf + 4 * (size_t)i) = o;
      }
    }
    return;
  }

  // ---- lv2 P tiles (T=4) ----
  int b = blockIdx.x;
  const int T = 4;
  const int rb = b % T; b /= T;
  const int jb = b % T; b /= T;
  const int c = b;
  const int h = 64 * T;
  const int base = c * 2 * h;

  const int tid = threadIdx.x;
  const int k4 = tid & 15;
  const int rw = tid >> 4;
  const int tm = tid >> 4;
  const int tn = tid & 15;
  float acc[4][4];
  ZERO_ACC;

  for (int kb = jb; kb < T; ++kb) {
    STAGE_T(Ls, MT, base + 64 * jb, base + 64 * kb, KDIM);
    STAGE_T(Rs, A, base + h + 64 * rb, base + 64 * kb, KDIM);
    __syncthreads();
    mac64(Ls, Rs, tm, tn, acc);
    __syncthreads();
  }

  float* P0 = Pt + (size_t)c * h * h;
#pragma unroll
  for (int a = 0; a < 4; ++a)
    *(float4*)(P0 + (size_t)(64 * jb + 4 * tm + a) * h + 64 * rb + 4 * tn) =
        make_float4(acc[a][0], acc[a][1], acc[a][2], acc[a][3]);
}

// ---------------------------------------------------------------------------
// p_k<T>: lv3 P tiles (unchanged).  q_k<T>: Q tiles + Mbf mirror (unchanged).
// ---------------------------------------------------------------------------
template <int T>
__global__ __launch_bounds__(256) void p_k(const float* __restrict__ A,
                                           const float* __restrict__ MT,
                                           float* __restrict__ Pt) {
  int b = blockIdx.x;
  const int rb = b % T; b /= T;
  const int jb = b % T; b /= T;
  const int c = b;
  const int h = 64 * T;
  const int base = c * 2 * h;

  __shared__ float Ls[64][68];
  __shared__ float Rs[64][68];
  const int tid = threadIdx.x;
  const int k4 = tid & 15;
  const int rw = tid >> 4;
  const int tm = tid >> 4;
  const int tn = tid & 15;
  float acc[4][4];
  ZERO_ACC;

  for (int kb = jb; kb < T; ++kb) {
    STAGE_T(Ls, MT, base + 64 * jb, base + 64 * kb, KDIM);
    STAGE_T(Rs, A, base + h + 64 * rb, base + 64 * kb, KDIM);
    __syncthreads();
    mac64(Ls, Rs, tm, tn, acc);
    __syncthreads();
  }

  float* P0 = Pt + (size_t)c * h * h;
#pragma unroll
  for (int a = 0; a < 4; ++a)
    *(float4*)(P0 + (size_t)(64 * jb + 4 * tm + a) * h + 64 * rb + 4 * tn) =
        make_float4(acc[a][0], acc[a][1], acc[a][2], acc[a][3]);
}

template <int T>
__global__ __launch_bounds__(256) void q_k(float* __restrict__ MT,
                                           const float* __restrict__ Pt,
                                           unsigned short* __restrict__ Mbf) {
  int b = blockIdx.x;
  const int rb = b % T; b /= T;
  const int jb = b % T; b /= T;
  const int c = b;
  const int h = 64 * T;
  const int base = c * 2 * h;

  __shared__ float Ls[64][68];
  __shared__ float Rs[64][68];
  const int tid = threadIdx.x;
  const int k4 = tid & 15;
  const int rw = tid >> 4;
  const int tm = tid >> 4;
  const int tn = tid & 15;
  float acc[4][4];
  ZERO_ACC;

  const float* P0 = Pt + (size_t)c * h * h;
  for (int kb = 0; kb <= rb; ++kb) {
    STAGE_T(Ls, P0, 64 * jb, 64 * kb, h);
    STAGE_D(Rs, MT, base + h + 64 * kb, base + h + 64 * rb, KDIM);
    __syncthreads();
    mac64(Ls, Rs, tm, tn, acc);
    __syncthreads();
  }

  STORE_MT(base + 64 * jb, base + h + 64 * rb);
  MBF_TILE(base + 64 * jb, base + h + 64 * rb, Ls);
}

// ---------------------------------------------------------------------------
// bf16 MFMA GEMM with fused per-sample correction.
//   C[b][i] = sum_k Z[b][k] * M[i][k]  +  coef_b * M[i][t_b]
//   coef_b  = (mean + exp(lsc) * z[b][t_b]) - dot(Zbf[b,:], Mbf[t_b,:])
// The dot uses the SAME bf16 inputs as the MFMA, so the correction matches
// the previous read-out-then-fix pass to fp32 ordering effects.
// M[i][t_b] is read as MT[t_b][col]: contiguous in col -> coalesced gather.
// ---------------------------------------------------------------------------
#define LDB 72

template <int ZBF>
__global__ __launch_bounds__(256) void gemm_mfma(
    const float* __restrict__ Z, const unsigned short* __restrict__ Zbf,
    const unsigned short* __restrict__ Mbf, const float* __restrict__ MT,
    const int* __restrict__ tgt, const int* __restrict__ var,
    const float* __restrict__ means, const float* __restrict__ lsc,
    float* __restrict__ C) {
  __shared__ unsigned short As[128][LDB];
  __shared__ unsigned short Bs[128][LDB];
  __shared__ float scoef[128];
  __shared__ int stb[128];

  const int d = blockIdx.x;
  const int xbl = d & 7;
  const int nir = (d >> 3) & 7;
  const int xbh = d >> 6;
  const int xb = xbh * 8 + xbl;
  const int ni = (xb & 32) ? (7 - nir) : nir;
  const int b0 = xb * 128;
  const int i0 = ni * 128;

  const int tid = threadIdx.x;
  const int w = tid >> 6;
  const int lane = tid & 63;
  const int wr = w >> 1, wc = w & 1;
  const int mlane = lane & 15;
  const int q = lane >> 4;

  const int rq = tid >> 4, kq = tid & 15;
  const int cb = tid >> 3, ck = tid & 7;

  f32x4 acc[4][4];
#pragma unroll
  for (int a = 0; a < 4; ++a)
#pragma unroll
    for (int b = 0; b < 4; ++b) acc[a][b] = (f32x4){0.f, 0.f, 0.f, 0.f};

  const int nkb = 2 * (ni + 1);
  for (int kb = 0; kb < nkb; ++kb) {
    const int k0 = kb * 64;
    if (ZBF) {
#pragma unroll
      for (int p = 0; p < 4; ++p) {
        const int r = p * 32 + cb;
        *(uint4*)&As[r][8 * ck] =
            *(const uint4*)(Zbf + (size_t)(b0 + r) * KDIM + k0 + 8 * ck);
      }
    } else {
#pragma unroll
      for (int p = 0; p < 8; ++p) {
        const int r = p * 16 + rq;
        float4 zv = *(const float4*)(Z + (size_t)(b0 + r) * KDIM + k0 + 4 * kq);
        ushort4 o;
        o.x = f2bf(zv.x);
        o.y = f2bf(zv.y);
        o.z = f2bf(zv.z);
        o.w = f2bf(zv.w);
        *(ushort4*)&As[r][4 * kq] = o;
      }
    }
#pragma unroll
    for (int p = 0; p < 4; ++p) {
      const int c = p * 32 + cb;
      *(uint4*)&Bs[c][8 * ck] =
          *(const uint4*)(Mbf + (size_t)(i0 + c) * KDIM + k0 + 8 * ck);
    }
    __syncthreads();
#pragma unroll
    for (int ks = 0; ks < 2; ++ks) {
      const int kf = ks * 32 + q * 8;
      short8 av[4], bv[4];
#pragma unroll
      for (int a = 0; a < 4; ++a)
        av[a] = *(const short8*)&As[wr * 64 + 16 * a + mlane][kf];
#pragma unroll
      for (int b = 0; b < 4; ++b)
        bv[b] = *(const short8*)&Bs[wc * 64 + 16 * b + mlane][kf];
#pragma unroll
      for (int a = 0; a < 4; ++a)
#pragma unroll
        for (int b = 0; b < 4; ++b)
          acc[a][b] =
              __builtin_amdgcn_mfma_f32_16x16x32_bf16(av[a], bv[b], acc[a][b], 0, 0, 0);
    }
    __syncthreads();
  }

  // ---- fused correction: coef for this block's 128 samples ----
  {
    const int s = tid >> 1, h2 = tid & 1;  // 2 threads per sample
    const int br = b0 + s;
    const int tb = tgt[br];
    float part = 0.f;
    if (tb >= 0) {
      const int nk16 = (tb >> 4) + 1;  // 16-elem chunks covering k <= tb
      if (ZBF) {
        const unsigned short* zr = Zbf + (size_t)br * KDIM;
        const unsigned short* mr = Mbf + (size_t)tb * KDIM;
        for (int c16 = h2; c16 < nk16; c16 += 2) {
          const uint4 za = *(const uint4*)(zr + c16 * 16);
          const uint4 zb2 = *(const uint4*)(zr + c16 * 16 + 8);
          const uint4 ma = *(const uint4*)(mr + c16 * 16);
          const uint4 mb2 = *(const uint4*)(mr + c16 * 16 + 8);
          const unsigned zw[8] = {za.x, za.y, za.z, za.w,
                                  zb2.x, zb2.y, zb2.z, zb2.w};
          const unsigned mw[8] = {ma.x, ma.y, ma.z, ma.w,
                                  mb2.x, mb2.y, mb2.z, mb2.w};
#pragma unroll
          for (int wv = 0; wv < 8; ++wv) {
            part += __builtin_bit_cast(float, zw[wv] << 16) *
                    __builtin_bit_cast(float, mw[wv] << 16);
            part += __builtin_bit_cast(float, zw[wv] & 0xFFFF0000u) *
                    __builtin_bit_cast(float, mw[wv] & 0xFFFF0000u);
          }
        }
      } else {
        const float* zr = Z + (size_t)br * KDIM;
        const unsigned short* mr = Mbf + (size_t)tb * KDIM;
        const int nk8 = (tb >> 3) + 1;
        for (int c8 = h2; c8 < nk8; c8 += 2) {
          const float4 z0 = *(const float4*)(zr + c8 * 8);
          const float4 z1 = *(const float4*)(zr + c8 * 8 + 4);
          const ushort4 m0 = *(const ushort4*)(mr + c8 * 8);
          const ushort4 m1 = *(const ushort4*)(mr + c8 * 8 + 4);
          part += z0.x * bf2f(m0.x) + z0.y * bf2f(m0.y) + z0.z * bf2f(m0.z) +
                  z0.w * bf2f(m0.w) + z1.x * bf2f(m1.x) + z1.y * bf2f(m1.y) +
                  z1.z * bf2f(m1.z) + z1.w * bf2f(m1.w);
        }
      }
    }
    part += __shfl_down(part, 1);  // pair (2s, 2s+1) within wave
    if (h2 == 0) {
      float cf = 0.f;
      int tbs = 0;
      if (tb >= 0) {
        const int v = var[br];
        const float mval = means[tb * VDIM + v];
        const float sval = expf(lsc[tb * VDIM + v]);
        const float zv = Z[(size_t)br * KDIM + tb];
        cf = (mval + sval * zv) - part;
        tbs = tb;
      }
      scoef[s] = cf;
      stb[s] = tbs;
    }
  }
  __syncthreads();

#pragma unroll
  for (int a = 0; a < 4; ++a) {
    const int l0 = wr * 64 + 16 * a + q * 4;
    const int row0 = b0 + l0;
#pragma unroll
    for (int b = 0; b < 4; ++b) {
      const int col = i0 + wc * 64 + 16 * b + mlane;
      float* Cp = C + (size_t)row0 * KDIM + col;
#pragma unroll
      for (int j = 0; j < 4; ++j) {
        const float cf = scoef[l0 + j];
        const float corr = cf * MT[(size_t)stb[l0 + j] * KDIM + col];
        Cp[j * KDIM] = acc[a][b][j] + corr;
      }
    }
  }
}

// ---------------------------------------------------------------------------
extern "C" void kernel_launch(void* const* d_in, const int* in_sizes, int n_in,
                              void* d_out, int out_size, void* d_ws,
                              size_t ws_size, hipStream_t stream) {
  const float* z = (const float*)d_in[0];
  const int* tgt = (const int*)d_in[1];
  const int* var = (const int*)d_in[2];
  const float* A = (const float*)d_in[3];
  const float* means = (const float*)d_in[4];
  const float* lsc = (const float*)d_in[5];
  float* out = (float*)d_out;

  char* ws = (char*)d_ws;
  float* MT = (float*)ws;                                    // 4 MB
  unsigned short* Mbf = (unsigned short*)(ws + (4u << 20));  // 2 MB
  float* Pt2 = (float*)(ws + (6u << 20));                    // 0.5 MB
  float* Pt3 = (float*)(ws + (6u << 20) + (512u << 10));     // 1 MB
  unsigned short* Zbf = (unsigned short*)(ws + (7u << 20) + (512u << 10));
  const int use_zbf =
      ws_size >= (7u << 20) + (512u << 10) + (size_t)BDIM * KDIM * 2 ? 1 : 0;

  hipLaunchKernelGGL(prep_inv, dim3(NBLK), dim3(256), 0, stream, A, MT, Mbf);
  hipLaunchKernelGGL(comb01, dim3(16), dim3(256), 0, stream, A, MT, Mbf);
  hipLaunchKernelGGL(p4_stream, dim3(512), dim3(256), 0, stream, A, MT, Pt2, z,
                     Zbf, Mbf, use_zbf);
  hipLaunchKernelGGL((q_k<4>), dim3(32), dim3(256), 0, stream, MT, Pt2, Mbf);
  hipLaunchKernelGGL((p_k<8>), dim3(64), dim3(256), 0, stream, A, MT, Pt3);
  hipLaunchKernelGGL((q_k<8>), dim3(64), dim3(256), 0, stream, MT, Pt3, Mbf);
  if (use_zbf)
    hipLaunchKernelGGL((gemm_mfma<1>), dim3((BDIM / 128) * (KDIM / 128)),
                       dim3(256), 0, stream, z, Zbf, Mbf, MT, tgt, var, means,
                       lsc, out);
  else
    hipLaunchKernelGGL((gemm_mfma<0>), dim3((BDIM / 128) * (KDIM / 128)),
                       dim3(256), 0, stream, z, Zbf, Mbf, MT, tgt, var, means,
                       lsc, out);
}